// Round 1
// 408.789 us; speedup vs baseline: 1.2276x; 1.2276x over previous
//
#include <hip/hip_runtime.h>
#include <math.h>

// ---------------------------------------------------------------------------
// Round 6: decoder2_fused v3 — latency-bound fix.
//  - BM 128->64 (acc[4][4]=64 regs, launch_bounds(512,4) -> <=128 regs/wave
//    -> 2 blocks/CU co-resident; old version was 1 block/CU).
//  - grid 768 = 3*256 (balanced; old 384 = 1.5*256 had a half-idle tail).
//  - double-buffered LDS (2x36KB), next-tile global_load_lds issued BEFORE
//    current-tile MFMA, single barrier per kt -> drain hidden under compute.
//  - epilogue sinh/cosh via __expf (4 exps) instead of ocml sinhf/coshf.
// ---------------------------------------------------------------------------

constexpr int Tn  = 6;
constexpr int Dn  = 256;
constexpr int Hn  = 512;
constexpr int NBn = 5;
constexpr int OUTn = 401;
constexpr int BA  = 8192;
constexpr int MR  = 49152;
constexpr float kAlpha = 0.5f;
constexpr float kBeta  = 0.5f;

typedef __bf16 bf16_8 __attribute__((ext_vector_type(8)));
typedef float  f32x4  __attribute__((ext_vector_type(4)));

__device__ __forceinline__ void async_copy16(const __bf16* g, __bf16* l) {
  __builtin_amdgcn_global_load_lds(
      (const __attribute__((address_space(1))) void*)g,
      (__attribute__((address_space(3))) void*)l, 16, 0, 0);
}

// ---- generic GEMM (kept for tiny anchor GEMMs + decoder-1) -----------------
template<bool RELU, bool OUT_BF16>
__global__ __launch_bounds__(256) void gemm_mfma(
    const __bf16* __restrict__ A, const __bf16* __restrict__ BT,
    const float* __restrict__ bias, void* __restrict__ Cout,
    int M, int N, int K)
{
  __shared__ __align__(16) char smem[128 * 136 * 2];
  __bf16* As = (__bf16*)smem;
  __bf16* Bs = As + 128 * 32;

  const int tid = threadIdx.x;
  const int l   = tid & 63;
  const int w   = tid >> 6;
  const int wm  = w >> 1, wn = w & 1;

  const int GX = gridDim.x;
  const int total = GX * gridDim.y;
  const int L = blockIdx.y * GX + blockIdx.x;
  const int xcd = L & 7, pos = L >> 3;
  const int base = total >> 3, rem = total & 7;
  const int start = xcd * base + (xcd < rem ? xcd : rem);
  const int TL = start + pos;
  const int my = TL / GX;
  const int nx = TL - my * GX;
  const int m0 = my * 128;
  const int n0 = nx * 128;

  const int lrow = l >> 2;
  const int lk   = (l & 3) * 8;
  int ar0 = m0 + w * 32 + lrow;        if (ar0 > M - 1) ar0 = M - 1;
  int ar1 = m0 + w * 32 + 16 + lrow;   if (ar1 > M - 1) ar1 = M - 1;
  int br0 = n0 + w * 32 + lrow;        if (br0 > N - 1) br0 = N - 1;
  int br1 = n0 + w * 32 + 16 + lrow;   if (br1 > N - 1) br1 = N - 1;
  const __bf16* Ag0 = A  + (size_t)ar0 * K + lk;
  const __bf16* Ag1 = A  + (size_t)ar1 * K + lk;
  const __bf16* Bg0 = BT + (size_t)br0 * K + lk;
  const __bf16* Bg1 = BT + (size_t)br1 * K + lk;
  __bf16* Al = As + w * 1024;
  __bf16* Bl = Bs + w * 1024;

  f32x4 acc[4][4];
#pragma unroll
  for (int i = 0; i < 4; ++i)
#pragma unroll
    for (int j = 0; j < 4; ++j) acc[i][j] = (f32x4){0.f, 0.f, 0.f, 0.f};

  const __bf16* ap = As + (wm * 64 + (l & 15)) * 32 + (l >> 4) * 8;
  const __bf16* bp = Bs + (wn * 64 + (l & 15)) * 32 + (l >> 4) * 8;

  const int kIters = K >> 5;
  for (int kt = 0; kt < kIters; ++kt) {
    const int ko = kt * 32;
    async_copy16(Ag0 + ko, Al);
    async_copy16(Ag1 + ko, Al + 512);
    async_copy16(Bg0 + ko, Bl);
    async_copy16(Bg1 + ko, Bl + 512);
    __syncthreads();

    bf16_8 af[4], bf[4];
#pragma unroll
    for (int i = 0; i < 4; ++i) af[i] = *(const bf16_8*)(ap + i * 16 * 32);
#pragma unroll
    for (int j = 0; j < 4; ++j) bf[j] = *(const bf16_8*)(bp + j * 16 * 32);
#pragma unroll
    for (int i = 0; i < 4; ++i)
#pragma unroll
      for (int j = 0; j < 4; ++j)
        acc[i][j] = __builtin_amdgcn_mfma_f32_16x16x32_bf16(af[i], bf[j], acc[i][j], 0, 0, 0);
    __syncthreads();
  }

  const int colb = n0 + wn * 64 + (l & 15);
  const int rowb = m0 + wm * 64 + (l >> 4) * 4;

  if (OUT_BF16) {
    __bf16* Cs = (__bf16*)smem;
    const int lrb = wm * 64 + (l >> 4) * 4;
    const int lcb = wn * 64 + (l & 15);
#pragma unroll
    for (int j = 0; j < 4; ++j) {
      const float bj = bias[colb + j * 16];
#pragma unroll
      for (int i = 0; i < 4; ++i) {
#pragma unroll
        for (int r = 0; r < 4; ++r) {
          float v = acc[i][j][r] + bj;
          if (RELU) v = fmaxf(v, 0.0f);
          Cs[(lrb + i * 16 + r) * 136 + lcb + j * 16] = (__bf16)v;
        }
      }
    }
    __syncthreads();
    __bf16* Cg = (__bf16*)Cout;
#pragma unroll
    for (int it = 0; it < 8; ++it) {
      const int idx = it * 256 + tid;
      const int row = idx >> 4, c16 = idx & 15;
      const int gr = m0 + row;
      if (gr < M) {
        uint4 v = *(const uint4*)(Cs + row * 136 + c16 * 8);
        *(uint4*)(Cg + (size_t)gr * N + n0 + c16 * 8) = v;
      }
    }
  } else {
#pragma unroll
    for (int j = 0; j < 4; ++j) {
      const int gc = colb + j * 16;
      if (gc >= N) continue;
      const float bj = bias[gc];
#pragma unroll
      for (int i = 0; i < 4; ++i) {
        const int gr0 = rowb + i * 16;
#pragma unroll
        for (int r = 0; r < 4; ++r) {
          const int gr = gr0 + r;
          if (gr >= M) continue;
          float v = acc[i][j][r] + bj;
          if (RELU) v = fmaxf(v, 0.0f);
          ((float*)Cout)[(size_t)gr * N + gc] = v;
        }
      }
    }
  }
}

// ---- fused 2-layer c-MLP: Out = (relu(X@W1T^T+b1))@W2T^T+b2 ----------------
// X:(BA,256) bf16. BM=32, 256 threads, 4 waves. h in LDS, pre-tiled [kt][32][32].
__global__ __launch_bounds__(256) void mlp2_c(
    const __bf16* __restrict__ X, const __bf16* __restrict__ W1T,
    const float* __restrict__ b1, const __bf16* __restrict__ W2T,
    const float* __restrict__ b2, __bf16* __restrict__ Out)
{
  __shared__ __align__(16) __bf16 Ast[32 * 32];    //  2 KB
  __shared__ __align__(16) __bf16 Wst[256 * 32];   // 16 KB
  __shared__ __align__(16) __bf16 Hb[8 * 32 * 32]; // 16 KB
  const int tid = threadIdx.x, l = tid & 63, w = tid >> 6;
  const int m0 = blockIdx.x * 32;
  const int q4 = (l >> 4) * 4;

  f32x4 acc[2][4];
#pragma unroll
  for (int i = 0; i < 2; ++i)
#pragma unroll
    for (int j = 0; j < 4; ++j) acc[i][j] = (f32x4){0.f, 0.f, 0.f, 0.f};

  // ---- layer 1 ----
  for (int kt = 0; kt < 8; ++kt) {
    const int ko = kt * 32;
    if (tid < 128) {                       // waves 0,1 full: A tile 128 chunks
      const int ch = tid, row = ch >> 2, kk = (ch & 3) * 8;
      async_copy16(X + (size_t)(m0 + row) * Dn + ko + kk, Ast + ch * 8);
    }
#pragma unroll
    for (int r4 = 0; r4 < 4; ++r4) {       // W tile 1024 chunks
      const int ch = tid + r4 * 256, row = ch >> 2, kk = (ch & 3) * 8;
      async_copy16(W1T + (size_t)row * Dn + ko + kk, Wst + ch * 8);
    }
    __syncthreads();
    bf16_8 bf[4];
#pragma unroll
    for (int j = 0; j < 4; ++j)
      bf[j] = *(const bf16_8*)(Wst + (w * 64 + j * 16 + (l & 15)) * 32 + (l >> 4) * 8);
#pragma unroll
    for (int i = 0; i < 2; ++i) {
      bf16_8 af = *(const bf16_8*)(Ast + (i * 16 + (l & 15)) * 32 + (l >> 4) * 8);
#pragma unroll
      for (int j = 0; j < 4; ++j)
        acc[i][j] = __builtin_amdgcn_mfma_f32_16x16x32_bf16(af, bf[j], acc[i][j], 0, 0, 0);
    }
    __syncthreads();
  }

  // h = relu(acc + b1) -> pre-tiled LDS
#pragma unroll
  for (int j = 0; j < 4; ++j) {
    const int col = w * 64 + j * 16 + (l & 15);
    const float bj = b1[col];
    __bf16* hc = Hb + (col >> 5) * 1024 + (col & 31);
#pragma unroll
    for (int i = 0; i < 2; ++i)
#pragma unroll
      for (int r = 0; r < 4; ++r) {
        const int row = i * 16 + q4 + r;
        hc[row * 32] = (__bf16)fmaxf(acc[i][j][r] + bj, 0.0f);
      }
  }
  __syncthreads();

  // ---- layer 2 ----
#pragma unroll
  for (int i = 0; i < 2; ++i)
#pragma unroll
    for (int j = 0; j < 4; ++j) acc[i][j] = (f32x4){0.f, 0.f, 0.f, 0.f};
  for (int kt = 0; kt < 8; ++kt) {
    const int ko = kt * 32;
#pragma unroll
    for (int r4 = 0; r4 < 4; ++r4) {
      const int ch = tid + r4 * 256, row = ch >> 2, kk = (ch & 3) * 8;
      async_copy16(W2T + (size_t)row * Dn + ko + kk, Wst + ch * 8);
    }
    __syncthreads();
    bf16_8 bf[4];
#pragma unroll
    for (int j = 0; j < 4; ++j)
      bf[j] = *(const bf16_8*)(Wst + (w * 64 + j * 16 + (l & 15)) * 32 + (l >> 4) * 8);
#pragma unroll
    for (int i = 0; i < 2; ++i) {
      bf16_8 af = *(const bf16_8*)(Hb + kt * 1024 + (i * 16 + (l & 15)) * 32 + (l >> 4) * 8);
#pragma unroll
      for (int j = 0; j < 4; ++j)
        acc[i][j] = __builtin_amdgcn_mfma_f32_16x16x32_bf16(af, bf[j], acc[i][j], 0, 0, 0);
    }
    __syncthreads();
  }

#pragma unroll
  for (int j = 0; j < 4; ++j) {
    const int col = w * 64 + j * 16 + (l & 15);
    const float bj = b2[col];
#pragma unroll
    for (int i = 0; i < 2; ++i)
#pragma unroll
      for (int r = 0; r < 4; ++r) {
        const int row = i * 16 + q4 + r;
        Out[(size_t)(m0 + row) * Dn + col] = (__bf16)(acc[i][j][r] + bj);
      }
  }
}

// ---- fused 2-layer s-MLP + elementwise update ------------------------------
// BM=96 rows = 16 complete (ba) groups. Updates S and C masters in place.
__global__ __launch_bounds__(256) void mlp2_s(
    __bf16* __restrict__ S, const __bf16* __restrict__ W1T,
    const float* __restrict__ b1, const __bf16* __restrict__ W2T,
    const float* __restrict__ b2, const __bf16* __restrict__ Cnew,
    __bf16* __restrict__ C)
{
  // 70 KB: Ast 6K | Wst 16K | Hb 48K ; Snew (50.7K) overlays from offset 0.
  __shared__ __align__(16) char smem[71680];
  __bf16* Ast  = (__bf16*)smem;             // 96*32
  __bf16* Wst  = (__bf16*)(smem + 6144);    // 256*32
  __bf16* Hb   = (__bf16*)(smem + 22528);   // 8*96*32 pre-tiled
  __bf16* Snew = (__bf16*)smem;             // 96*264 (post-GEMM only)

  const int tid = threadIdx.x, l = tid & 63, w = tid >> 6;
  const int m0 = blockIdx.x * 96;
  const int q4 = (l >> 4) * 4;

  f32x4 acc[6][4];
#pragma unroll
  for (int i = 0; i < 6; ++i)
#pragma unroll
    for (int j = 0; j < 4; ++j) acc[i][j] = (f32x4){0.f, 0.f, 0.f, 0.f};

  // ---- layer 1 ----
  for (int kt = 0; kt < 8; ++kt) {
    const int ko = kt * 32;
    { const int ch = tid, row = ch >> 2, kk = (ch & 3) * 8;          // rows 0..63
      async_copy16(S + (size_t)(m0 + row) * Dn + ko + kk, Ast + ch * 8); }
    if (tid < 128) {                                                  // rows 64..95
      const int ch = 256 + tid, row = ch >> 2, kk = (ch & 3) * 8;
      async_copy16(S + (size_t)(m0 + row) * Dn + ko + kk, Ast + ch * 8);
    }
#pragma unroll
    for (int r4 = 0; r4 < 4; ++r4) {
      const int ch = tid + r4 * 256, row = ch >> 2, kk = (ch & 3) * 8;
      async_copy16(W1T + (size_t)row * Dn + ko + kk, Wst + ch * 8);
    }
    __syncthreads();
    bf16_8 bf[4];
#pragma unroll
    for (int j = 0; j < 4; ++j)
      bf[j] = *(const bf16_8*)(Wst + (w * 64 + j * 16 + (l & 15)) * 32 + (l >> 4) * 8);
#pragma unroll
    for (int i = 0; i < 6; ++i) {
      bf16_8 af = *(const bf16_8*)(Ast + (i * 16 + (l & 15)) * 32 + (l >> 4) * 8);
#pragma unroll
      for (int j = 0; j < 4; ++j)
        acc[i][j] = __builtin_amdgcn_mfma_f32_16x16x32_bf16(af, bf[j], acc[i][j], 0, 0, 0);
    }
    __syncthreads();
  }

  // h = relu(acc + b1) -> pre-tiled LDS [kt][96][32]
#pragma unroll
  for (int j = 0; j < 4; ++j) {
    const int col = w * 64 + j * 16 + (l & 15);
    const float bj = b1[col];
    __bf16* hc = Hb + (col >> 5) * (96 * 32) + (col & 31);
#pragma unroll
    for (int i = 0; i < 6; ++i)
#pragma unroll
      for (int r = 0; r < 4; ++r) {
        const int row = i * 16 + q4 + r;
        hc[row * 32] = (__bf16)fmaxf(acc[i][j][r] + bj, 0.0f);
      }
  }
  __syncthreads();

  // ---- layer 2 ----
#pragma unroll
  for (int i = 0; i < 6; ++i)
#pragma unroll
    for (int j = 0; j < 4; ++j) acc[i][j] = (f32x4){0.f, 0.f, 0.f, 0.f};
  for (int kt = 0; kt < 8; ++kt) {
    const int ko = kt * 32;
#pragma unroll
    for (int r4 = 0; r4 < 4; ++r4) {
      const int ch = tid + r4 * 256, row = ch >> 2, kk = (ch & 3) * 8;
      async_copy16(W2T + (size_t)row * Dn + ko + kk, Wst + ch * 8);
    }
    __syncthreads();
    bf16_8 bf[4];
#pragma unroll
    for (int j = 0; j < 4; ++j)
      bf[j] = *(const bf16_8*)(Wst + (w * 64 + j * 16 + (l & 15)) * 32 + (l >> 4) * 8);
#pragma unroll
    for (int i = 0; i < 6; ++i) {
      bf16_8 af = *(const bf16_8*)(Hb + kt * (96 * 32) + (i * 16 + (l & 15)) * 32 + (l >> 4) * 8);
#pragma unroll
      for (int j = 0; j < 4; ++j)
        acc[i][j] = __builtin_amdgcn_mfma_f32_16x16x32_bf16(af, bf[j], acc[i][j], 0, 0, 0);
    }
    __syncthreads();
  }

  // snew (raw, +b2) -> LDS (stride 264: 2-way max bank aliasing)
#pragma unroll
  for (int j = 0; j < 4; ++j) {
    const int col = w * 64 + j * 16 + (l & 15);
    const float bj = b2[col];
#pragma unroll
    for (int i = 0; i < 6; ++i)
#pragma unroll
      for (int r = 0; r < 4; ++r) {
        const int row = i * 16 + q4 + r;
        Snew[row * 264 + col] = (__bf16)(acc[i][j][r] + bj);
      }
  }
  __syncthreads();

  // fused elementwise update: 16 ba-groups x 32 d-chunks = 512 tasks
#pragma unroll
  for (int p = 0; p < 2; ++p) {
    const int q = p * 256 + tid;
    const int ba = q >> 5, dg = (q & 31) * 8;
    const size_t gb = (size_t)(blockIdx.x * 16 + ba) * Dn + dg;
    bf16_8 cn8 = *(const bf16_8*)(Cnew + gb);
    float cn[8], m[8];
#pragma unroll
    for (int e = 0; e < 8; ++e) { cn[e] = (float)cn8[e]; m[e] = -3.402823466e38f; }
#pragma unroll
    for (int t = 0; t < Tn; ++t) {
      const int row = ba * 6 + t;
      bf16_8 sn8 = *(const bf16_8*)(Snew + row * 264 + dg);
      const size_t gs = (size_t)(m0 + row) * Dn + dg;
      bf16_8 s8 = *(const bf16_8*)(S + gs);
      bf16_8 o8;
#pragma unroll
      for (int e = 0; e < 8; ++e) {
        const float sn = (float)sn8[e] * cn[e];
        m[e] = fmaxf(m[e], sn);
        o8[e] = (__bf16)(kAlpha * (float)s8[e] + kBeta * sn);
      }
      *(bf16_8*)(S + gs) = o8;
    }
    bf16_8 c8 = *(const bf16_8*)(C + gb);
#pragma unroll
    for (int e = 0; e < 8; ++e)
      c8[e] = (__bf16)(kAlpha * (float)c8[e] + kBeta * m[e]);
    *(bf16_8*)(C + gb) = c8;
  }
}

// ---- fused decoder-2 + covariance, v3 --------------------------------------
// BM=64, 512 threads, 768 blocks (=3*256, balanced), double-buffered LDS
// (2 x [Ast 4K | Bst 32K] = 72KB -> 2 blocks/CU with <=128 regs), one barrier
// per kt with next-tile prefetch issued before current-tile MFMA.
__global__ __launch_bounds__(512, 4) void decoder2_fused(
    const __bf16* __restrict__ A, const __bf16* __restrict__ BT,
    const float* __restrict__ bias, float* __restrict__ out)
{
  __shared__ __align__(16) char smem[73728];
  float* mid = (float*)smem;                  // 32*241 floats, post-loop only

  const int tid = threadIdx.x, l = tid & 63, w = tid >> 6;  // w 0..7
  const int m0 = blockIdx.x * 64;
  const int q4 = (l >> 4) * 4;

  f32x4 acc[4][4];
#pragma unroll
  for (int i = 0; i < 4; ++i)
#pragma unroll
    for (int j = 0; j < 4; ++j) acc[i][j] = (f32x4){0.f, 0.f, 0.f, 0.f};

  // staging source addresses (A: tid<256 stages 64x32; B: 4 chunks/thread)
  const __bf16* Ag = A + (size_t)(m0 + (tid >> 2)) * Hn + (tid & 3) * 8;
  const __bf16* Bg[4];
#pragma unroll
  for (int r4 = 0; r4 < 4; ++r4) {
    const int ch = tid + r4 * 512;
    int row = ch >> 2; if (row > 400) row = 400;
    Bg[r4] = BT + (size_t)row * Hn + (ch & 3) * 8;
  }

  auto stage = [&](int buf, int kt) {
    const int ko = kt * 32;
    __bf16* base = (__bf16*)(smem + buf * 36864);
    if (tid < 256) async_copy16(Ag + ko, base + tid * 8);
    __bf16* Bl = base + 64 * 32;
#pragma unroll
    for (int r4 = 0; r4 < 4; ++r4)
      async_copy16(Bg[r4] + ko, Bl + (size_t)(tid + r4 * 512) * 8);
  };

  stage(0, 0);
  __syncthreads();                            // drain prologue tile
  int cur = 0;
  for (int kt = 0; kt < 16; ++kt) {
    if (kt < 15) stage(cur ^ 1, kt + 1);      // issue next tile BEFORE compute
    const __bf16* Asl = (const __bf16*)(smem + cur * 36864);
    const __bf16* Bsl = Asl + 64 * 32;
    bf16_8 af[4], bf[4];
#pragma unroll
    for (int j = 0; j < 4; ++j)
      bf[j] = *(const bf16_8*)(Bsl + (w * 64 + j * 16 + (l & 15)) * 32 + (l >> 4) * 8);
#pragma unroll
    for (int i = 0; i < 4; ++i)
      af[i] = *(const bf16_8*)(Asl + (i * 16 + (l & 15)) * 32 + (l >> 4) * 8);
#pragma unroll
    for (int i = 0; i < 4; ++i)
#pragma unroll
      for (int j = 0; j < 4; ++j)
        acc[i][j] = __builtin_amdgcn_mfma_f32_16x16x32_bf16(af[i], bf[j], acc[i][j], 0, 0, 0);
    __syncthreads();                          // next tile staged + reads done
    cur ^= 1;
  }

  float* cov = out + MR + (size_t)MR * 160;
  const int gc = w * 64 + (l & 15);  // + j*16
#pragma unroll
  for (int sub = 0; sub < 2; ++sub) {
#pragma unroll
    for (int ih = 0; ih < 2; ++ih) {
      const int i = sub * 2 + ih;
#pragma unroll
      for (int j = 0; j < 4; ++j) {
        const int c = gc + j * 16;
        if (c > 400) continue;
        const float bj = bias[c];
#pragma unroll
        for (int r = 0; r < 4; ++r) {
          const int lr = ih * 16 + q4 + r;         // 0..31
          const int gr = m0 + sub * 32 + lr;
          const float v = acc[i][j][r] + bj;
          if (c < 160)      out[(size_t)MR + (size_t)gr * 160 + c] = v;
          else if (c < 400) mid[lr * 241 + (c - 160)] = v;
          else              out[gr] = v;
        }
      }
    }
    __syncthreads();
#pragma unroll
    for (int p = 0; p < 5; ++p) {
      const int q = p * 512 + tid;                 // 2560 tasks = 32 rows x 80
      const int r32 = q / 80, j = q - r32 * 80;
      const int gr = m0 + sub * 32 + r32;
      const float av = mid[r32 * 241 + j];
      const float bv = mid[r32 * 241 + 80 + j];
      const float cv = mid[r32 * 241 + 160 + j];
      const float eb = __expf(bv), ebn = __expf(-bv);
      const float sh = 0.5f * (eb - ebn), ch = 0.5f * (eb + ebn);
      const float ea = __expf(av), ean = __expf(-av), ec = __expf(cv);
      f32x4 c4 = { ea * ch * ec, sh * ec, sh * ec, ean * ch * ec };
      *(f32x4*)(cov + (size_t)gr * 320 + 4 * j) = c4;
    }
    if (sub == 0) __syncthreads();                 // protect mid before reuse
  }
}

// ---- weight transpose + bf16 convert ---------------------------------------
__global__ __launch_bounds__(256) void transpose_bf16(
    const float* __restrict__ W, __bf16* __restrict__ WT, int K, int N)
{
  __shared__ float t[32][33];
  const int b  = blockIdx.z;
  const int tx = threadIdx.x, ty = threadIdx.y;
  const int k0 = blockIdx.y * 32, n0 = blockIdx.x * 32;
  const float* Wb  = W  + (size_t)b * K * N;
  __bf16*      WTb = WT + (size_t)b * N * K;
#pragma unroll
  for (int r = 0; r < 4; ++r) {
    int kk = k0 + ty + r * 8;
    if (kk < K && n0 + tx < N) t[ty + r * 8][tx] = Wb[(size_t)kk * N + n0 + tx];
  }
  __syncthreads();
#pragma unroll
  for (int r = 0; r < 4; ++r) {
    int nn = n0 + ty + r * 8;
    if (nn < N && k0 + tx < K)
      WTb[(size_t)nn * K + k0 + tx] = (__bf16)t[tx][ty + r * 8];
  }
}

__global__ __launch_bounds__(256) void convert_bf16(
    const float* __restrict__ in, __bf16* __restrict__ out, int n)
{
  int i = blockIdx.x * 256 + threadIdx.x;
  if (i < n) out[i] = (__bf16)in[i];
}

// ---- iter-0 elementwise (init folded) --------------------------------------
__global__ __launch_bounds__(256) void ew_update0(
    const float* __restrict__ anchor, const float* __restrict__ fe,
    const float* __restrict__ snewsm, const __bf16* __restrict__ cnew,
    __bf16* __restrict__ s, __bf16* __restrict__ c)
{
  int q = blockIdx.x * 256 + threadIdx.x;
  if (q >= BA * 32) return;
  int ba = q >> 5;
  int dg = (q & 31) * 8;
  bf16_8 cn8 = *(const bf16_8*)(cnew + (size_t)ba * Dn + dg);
  float cn[8], m[8];
#pragma unroll
  for (int e = 0; e < 8; ++e) { cn[e] = (float)cn8[e]; m[e] = -3.402823466e38f; }
  size_t base = (size_t)ba * Tn * Dn + dg;
#pragma unroll
  for (int t = 0; t < Tn; ++t) {
    bf16_8 o8;
#pragma unroll
    for (int e = 0; e < 8; ++e) {
      float sn = snewsm[t * Dn + dg + e] * cn[e];
      m[e] = fmaxf(m[e], sn);
      o8[e] = (__bf16)(kAlpha * anchor[t * Dn + dg + e] + kBeta * sn);
    }
    *(bf16_8*)(s + base + t * Dn) = o8;
  }
  bf16_8 c8;
#pragma unroll
  for (int e = 0; e < 8; ++e)
    c8[e] = (__bf16)(kAlpha * fe[(size_t)ba * Dn + dg + e] + kBeta * m[e]);
  *(bf16_8*)(c + (size_t)ba * Dn + dg) = c8;
}

// ---------------------------------------------------------------------------
extern "C" void kernel_launch(void* const* d_in, const int* in_sizes, int n_in,
                              void* d_out, int out_size, void* d_ws, size_t ws_size,
                              hipStream_t stream) {
  const float* fe     = (const float*)d_in[0];
  const float* anchor = (const float*)d_in[1];
  const float* sW1 = (const float*)d_in[2];
  const float* sb1 = (const float*)d_in[3];
  const float* sW2 = (const float*)d_in[4];
  const float* sb2 = (const float*)d_in[5];
  const float* cW1 = (const float*)d_in[6];
  const float* cb1 = (const float*)d_in[7];
  const float* cW2 = (const float*)d_in[8];
  const float* cb2 = (const float*)d_in[9];
  const float* dW1 = (const float*)d_in[10];
  const float* db1 = (const float*)d_in[11];
  const float* dW2 = (const float*)d_in[12];
  const float* db2 = (const float*)d_in[13];
  float* out = (float*)d_out;

  // ---- workspace layout (bytes), total ~91.4 MB ----
  char* p = (char*)d_ws;
  __bf16* s_bf    = (__bf16*)(p + 0);            // 25,165,824
  __bf16* hd_bf   = (__bf16*)(p + 25165824);     // 50,331,648
  __bf16* c_bf    = (__bf16*)(p + 75497472);     //  4,194,304
  __bf16* cnew_bf = (__bf16*)(p + 79691776);     //  4,194,304
  __bf16* fe_bf   = (__bf16*)(p + 83886080);     //  4,194,304
  __bf16* sWT1    = (__bf16*)(p + 88080384);     //    655,360 each
  __bf16* sWT2    = (__bf16*)(p + 88735744);
  __bf16* cWT1    = (__bf16*)(p + 89391104);
  __bf16* cWT2    = (__bf16*)(p + 90046464);
  __bf16* dWT1    = (__bf16*)(p + 90701824);     //    262,144
  __bf16* dWT2    = (__bf16*)(p + 90963968);     //    410,624
  __bf16* anc_bf  = (__bf16*)(p + 91374592);     //      3,072
  __bf16* hsm_bf  = (__bf16*)(p + 91377664);     //      3,072
  float*  snewsm_f= (float* )(p + 91380736);     //      6,144

  auto gemm = [&](const __bf16* A, const __bf16* BT, const float* b, void* C,
                  int M, int N, int K, bool relu, bool outbf) {
    dim3 grid((N + 127) / 128, (M + 127) / 128);
    if (relu) {
      if (outbf) gemm_mfma<true,  true ><<<grid, 256, 0, stream>>>(A, BT, b, C, M, N, K);
      else       gemm_mfma<true,  false><<<grid, 256, 0, stream>>>(A, BT, b, C, M, N, K);
    } else {
      if (outbf) gemm_mfma<false, true ><<<grid, 256, 0, stream>>>(A, BT, b, C, M, N, K);
      else       gemm_mfma<false, false><<<grid, 256, 0, stream>>>(A, BT, b, C, M, N, K);
    }
  };

  // ---- weight prep ----
  {
    dim3 blk(32, 8);
    dim3 g88(8, 8, NBn);
    transpose_bf16<<<g88, blk, 0, stream>>>(sW1, sWT1, Dn, Dn);
    transpose_bf16<<<g88, blk, 0, stream>>>(sW2, sWT2, Dn, Dn);
    transpose_bf16<<<g88, blk, 0, stream>>>(cW1, cWT1, Dn, Dn);
    transpose_bf16<<<g88, blk, 0, stream>>>(cW2, cWT2, Dn, Dn);
    transpose_bf16<<<dim3(16, 8, 1), blk, 0, stream>>>(dW1, dWT1, Dn, Hn);
    transpose_bf16<<<dim3(13, 16, 1), blk, 0, stream>>>(dW2, dWT2, Hn, OUTn);
  }
  convert_bf16<<<(BA * Dn + 255) / 256, 256, 0, stream>>>(fe, fe_bf, BA * Dn);
  convert_bf16<<<(Tn * Dn + 255) / 256, 256, 0, stream>>>(anchor, anc_bf, Tn * Dn);

  const size_t WKK = (size_t)Dn * Dn;

  // ---- iteration 0 (s-branch on 6 anchor rows; c-branch fused MLP) ----
  gemm(anc_bf, sWT1, sb1, hsm_bf,   Tn, Dn, Dn, true,  true);
  gemm(hsm_bf, sWT2, sb2, snewsm_f, Tn, Dn, Dn, false, false);
  mlp2_c<<<BA / 32, 256, 0, stream>>>(fe_bf, cWT1, cb1, cWT2, cb2, cnew_bf);
  ew_update0<<<(BA * 32 + 255) / 256, 256, 0, stream>>>(anchor, fe, snewsm_f,
                                                        cnew_bf, s_bf, c_bf);

  // ---- iterations 1..4: two fused kernels each ----
  for (int i = 1; i < NBn; ++i) {
    mlp2_c<<<BA / 32, 256, 0, stream>>>(c_bf, cWT1 + i * WKK, cb1 + i * Dn,
                                        cWT2 + i * WKK, cb2 + i * Dn, cnew_bf);
    mlp2_s<<<MR / 96, 256, 0, stream>>>(s_bf, sWT1 + i * WKK, sb1 + i * Dn,
                                        sWT2 + i * WKK, sb2 + i * Dn,
                                        cnew_bf, c_bf);
  }

  // ---- decoder ----
  gemm(s_bf, dWT1, db1, hd_bf, MR, Hn, Dn, true, true);
  decoder2_fused<<<MR / 64, 512, 0, stream>>>(hd_bf, dWT2, db2, out);
}

// Round 2
// 393.353 us; speedup vs baseline: 1.2758x; 1.0392x over previous
//
#include <hip/hip_runtime.h>
#include <math.h>

// ---------------------------------------------------------------------------
// Round 7: pipeline the remaining latency-bound kernels.
//  - mlp2_c: 512 threads (8 waves x 32-col strips), fully double-buffered
//    staging (Ast 2x2K, Wst 2x16K), 1 barrier/kt both layers.
//  - mlp2_s: 512 threads (8 waves x 32-col strips, acc[6][2] -> 16 waves/CU),
//    layer-1 double-buffered by overlaying buf1 in the unused Hb region.
//  - gemm_mfma: double-buffered prefetch (2x16K under the 34K Cs overlay).
//  - decoder2_fused v3 unchanged (71.5us; floors ~24us, options exhausted).
// ---------------------------------------------------------------------------

constexpr int Tn  = 6;
constexpr int Dn  = 256;
constexpr int Hn  = 512;
constexpr int NBn = 5;
constexpr int OUTn = 401;
constexpr int BA  = 8192;
constexpr int MR  = 49152;
constexpr float kAlpha = 0.5f;
constexpr float kBeta  = 0.5f;

typedef __bf16 bf16_8 __attribute__((ext_vector_type(8)));
typedef float  f32x4  __attribute__((ext_vector_type(4)));

__device__ __forceinline__ void async_copy16(const __bf16* g, __bf16* l) {
  __builtin_amdgcn_global_load_lds(
      (const __attribute__((address_space(1))) void*)g,
      (__attribute__((address_space(3))) void*)l, 16, 0, 0);
}

// ---- generic GEMM (anchor GEMMs + decoder-1), double-buffered --------------
template<bool RELU, bool OUT_BF16>
__global__ __launch_bounds__(256) void gemm_mfma(
    const __bf16* __restrict__ A, const __bf16* __restrict__ BT,
    const float* __restrict__ bias, void* __restrict__ Cout,
    int M, int N, int K)
{
  // staging: buf b at smem + b*16384 (As 8K | Bs 8K); Cs epilogue overlay 34816.
  __shared__ __align__(16) char smem[34816];

  const int tid = threadIdx.x;
  const int l   = tid & 63;
  const int w   = tid >> 6;
  const int wm  = w >> 1, wn = w & 1;

  const int GX = gridDim.x;
  const int total = GX * gridDim.y;
  const int L = blockIdx.y * GX + blockIdx.x;
  const int xcd = L & 7, pos = L >> 3;
  const int base = total >> 3, rem = total & 7;
  const int start = xcd * base + (xcd < rem ? xcd : rem);
  const int TL = start + pos;
  const int my = TL / GX;
  const int nx = TL - my * GX;
  const int m0 = my * 128;
  const int n0 = nx * 128;

  const int lrow = l >> 2;
  const int lk   = (l & 3) * 8;
  int ar0 = m0 + w * 32 + lrow;        if (ar0 > M - 1) ar0 = M - 1;
  int ar1 = m0 + w * 32 + 16 + lrow;   if (ar1 > M - 1) ar1 = M - 1;
  int br0 = n0 + w * 32 + lrow;        if (br0 > N - 1) br0 = N - 1;
  int br1 = n0 + w * 32 + 16 + lrow;   if (br1 > N - 1) br1 = N - 1;
  const __bf16* Ag0 = A  + (size_t)ar0 * K + lk;
  const __bf16* Ag1 = A  + (size_t)ar1 * K + lk;
  const __bf16* Bg0 = BT + (size_t)br0 * K + lk;
  const __bf16* Bg1 = BT + (size_t)br1 * K + lk;

  f32x4 acc[4][4];
#pragma unroll
  for (int i = 0; i < 4; ++i)
#pragma unroll
    for (int j = 0; j < 4; ++j) acc[i][j] = (f32x4){0.f, 0.f, 0.f, 0.f};

  auto stage = [&](int buf, int ko) {
    __bf16* As = (__bf16*)(smem + buf * 16384);
    __bf16* Bs = As + 4096;
    async_copy16(Ag0 + ko, As + w * 1024);
    async_copy16(Ag1 + ko, As + w * 1024 + 512);
    async_copy16(Bg0 + ko, Bs + w * 1024);
    async_copy16(Bg1 + ko, Bs + w * 1024 + 512);
  };

  const int kIters = K >> 5;
  stage(0, 0);
  __syncthreads();
  for (int kt = 0; kt < kIters; ++kt) {
    if (kt + 1 < kIters) stage((kt + 1) & 1, (kt + 1) * 32);
    const __bf16* As = (const __bf16*)(smem + (kt & 1) * 16384);
    const __bf16* Bs = As + 4096;
    const __bf16* ap = As + (wm * 64 + (l & 15)) * 32 + (l >> 4) * 8;
    const __bf16* bp = Bs + (wn * 64 + (l & 15)) * 32 + (l >> 4) * 8;

    bf16_8 af[4], bf[4];
#pragma unroll
    for (int i = 0; i < 4; ++i) af[i] = *(const bf16_8*)(ap + i * 16 * 32);
#pragma unroll
    for (int j = 0; j < 4; ++j) bf[j] = *(const bf16_8*)(bp + j * 16 * 32);
#pragma unroll
    for (int i = 0; i < 4; ++i)
#pragma unroll
      for (int j = 0; j < 4; ++j)
        acc[i][j] = __builtin_amdgcn_mfma_f32_16x16x32_bf16(af[i], bf[j], acc[i][j], 0, 0, 0);
    __syncthreads();
  }

  const int colb = n0 + wn * 64 + (l & 15);
  const int rowb = m0 + wm * 64 + (l >> 4) * 4;

  if (OUT_BF16) {
    __bf16* Cs = (__bf16*)smem;
    const int lrb = wm * 64 + (l >> 4) * 4;
    const int lcb = wn * 64 + (l & 15);
#pragma unroll
    for (int j = 0; j < 4; ++j) {
      const float bj = bias[colb + j * 16];
#pragma unroll
      for (int i = 0; i < 4; ++i) {
#pragma unroll
        for (int r = 0; r < 4; ++r) {
          float v = acc[i][j][r] + bj;
          if (RELU) v = fmaxf(v, 0.0f);
          Cs[(lrb + i * 16 + r) * 136 + lcb + j * 16] = (__bf16)v;
        }
      }
    }
    __syncthreads();
    __bf16* Cg = (__bf16*)Cout;
#pragma unroll
    for (int it = 0; it < 8; ++it) {
      const int idx = it * 256 + tid;
      const int row = idx >> 4, c16 = idx & 15;
      const int gr = m0 + row;
      if (gr < M) {
        uint4 v = *(const uint4*)(Cs + row * 136 + c16 * 8);
        *(uint4*)(Cg + (size_t)gr * N + n0 + c16 * 8) = v;
      }
    }
  } else {
#pragma unroll
    for (int j = 0; j < 4; ++j) {
      const int gc = colb + j * 16;
      if (gc >= N) continue;
      const float bj = bias[gc];
#pragma unroll
      for (int i = 0; i < 4; ++i) {
        const int gr0 = rowb + i * 16;
#pragma unroll
        for (int r = 0; r < 4; ++r) {
          const int gr = gr0 + r;
          if (gr >= M) continue;
          float v = acc[i][j][r] + bj;
          if (RELU) v = fmaxf(v, 0.0f);
          ((float*)Cout)[(size_t)gr * N + gc] = v;
        }
      }
    }
  }
}

// ---- fused 2-layer c-MLP, v2: 512 threads, fully double-buffered -----------
// X:(BA,256) bf16, BM=32. 8 waves, wave w owns cols w*32..w*32+31 (acc[2][2]).
__global__ __launch_bounds__(512) void mlp2_c(
    const __bf16* __restrict__ X, const __bf16* __restrict__ W1T,
    const float* __restrict__ b1, const __bf16* __restrict__ W2T,
    const float* __restrict__ b2, __bf16* __restrict__ Out)
{
  // Ast bufs @0,2048 (2K) | Wst bufs @4096,20480 (16K) | Hb @36864 (16K)
  __shared__ __align__(16) char smem[53248];
  __bf16* Hb = (__bf16*)(smem + 36864);

  const int tid = threadIdx.x, l = tid & 63, w = tid >> 6;  // w 0..7
  const int m0 = blockIdx.x * 32;
  const int q4 = (l >> 4) * 4;

  f32x4 acc[2][2];
#pragma unroll
  for (int i = 0; i < 2; ++i)
#pragma unroll
    for (int j = 0; j < 2; ++j) acc[i][j] = (f32x4){0.f, 0.f, 0.f, 0.f};

  const __bf16* Xg = X + (size_t)(m0 + (tid >> 2)) * Dn + (tid & 3) * 8; // tid<128

  auto stageA = [&](int buf, int kt) {
    if (tid < 128)
      async_copy16(Xg + kt * 32, (__bf16*)(smem + buf * 2048) + tid * 8);
  };
  auto stageW = [&](const __bf16* WT, int buf, int kt) {
    __bf16* Wstb = (__bf16*)(smem + 4096 + buf * 16384);
#pragma unroll
    for (int r2 = 0; r2 < 2; ++r2) {
      const int ch = tid + r2 * 512, row = ch >> 2, kk = (ch & 3) * 8;
      async_copy16(WT + (size_t)row * Dn + kt * 32 + kk, Wstb + ch * 8);
    }
  };

  // ---- layer 1 ----
  stageA(0, 0); stageW(W1T, 0, 0);
  __syncthreads();
  for (int kt = 0; kt < 8; ++kt) {
    if (kt < 7) { stageA((kt + 1) & 1, kt + 1); stageW(W1T, (kt + 1) & 1, kt + 1); }
    const __bf16* Astb = (const __bf16*)(smem + (kt & 1) * 2048);
    const __bf16* Wstb = (const __bf16*)(smem + 4096 + (kt & 1) * 16384);
    bf16_8 bf[2];
#pragma unroll
    for (int j = 0; j < 2; ++j)
      bf[j] = *(const bf16_8*)(Wstb + (w * 32 + j * 16 + (l & 15)) * 32 + (l >> 4) * 8);
#pragma unroll
    for (int i = 0; i < 2; ++i) {
      bf16_8 af = *(const bf16_8*)(Astb + (i * 16 + (l & 15)) * 32 + (l >> 4) * 8);
#pragma unroll
      for (int j = 0; j < 2; ++j)
        acc[i][j] = __builtin_amdgcn_mfma_f32_16x16x32_bf16(af, bf[j], acc[i][j], 0, 0, 0);
    }
    __syncthreads();
  }

  // h = relu(acc + b1) -> pre-tiled LDS [kt][32][32]
#pragma unroll
  for (int j = 0; j < 2; ++j) {
    const int col = w * 32 + j * 16 + (l & 15);
    const float bj = b1[col];
    __bf16* hc = Hb + (col >> 5) * 1024 + (col & 31);
#pragma unroll
    for (int i = 0; i < 2; ++i)
#pragma unroll
      for (int r = 0; r < 4; ++r) {
        const int row = i * 16 + q4 + r;
        hc[row * 32] = (__bf16)fmaxf(acc[i][j][r] + bj, 0.0f);
      }
  }
  __syncthreads();

  // ---- layer 2 ----
#pragma unroll
  for (int i = 0; i < 2; ++i)
#pragma unroll
    for (int j = 0; j < 2; ++j) acc[i][j] = (f32x4){0.f, 0.f, 0.f, 0.f};
  stageW(W2T, 0, 0);
  __syncthreads();
  for (int kt = 0; kt < 8; ++kt) {
    if (kt < 7) stageW(W2T, (kt + 1) & 1, kt + 1);
    const __bf16* Wstb = (const __bf16*)(smem + 4096 + (kt & 1) * 16384);
    bf16_8 bf[2];
#pragma unroll
    for (int j = 0; j < 2; ++j)
      bf[j] = *(const bf16_8*)(Wstb + (w * 32 + j * 16 + (l & 15)) * 32 + (l >> 4) * 8);
#pragma unroll
    for (int i = 0; i < 2; ++i) {
      bf16_8 af = *(const bf16_8*)(Hb + kt * 1024 + (i * 16 + (l & 15)) * 32 + (l >> 4) * 8);
#pragma unroll
      for (int j = 0; j < 2; ++j)
        acc[i][j] = __builtin_amdgcn_mfma_f32_16x16x32_bf16(af, bf[j], acc[i][j], 0, 0, 0);
    }
    __syncthreads();
  }

#pragma unroll
  for (int j = 0; j < 2; ++j) {
    const int col = w * 32 + j * 16 + (l & 15);
    const float bj = b2[col];
#pragma unroll
    for (int i = 0; i < 2; ++i)
#pragma unroll
      for (int r = 0; r < 4; ++r) {
        const int row = i * 16 + q4 + r;
        Out[(size_t)(m0 + row) * Dn + col] = (__bf16)(acc[i][j][r] + bj);
      }
  }
}

// ---- fused 2-layer s-MLP + elementwise update, v2: 512 threads -------------
// BM=96 = 16 (ba) groups. 8 waves x 32-col strips (acc[6][2]).
// Layer-1 double-buffered: buf1 overlays the (not yet used) Hb region.
__global__ __launch_bounds__(512) void mlp2_s(
    __bf16* __restrict__ S, const __bf16* __restrict__ W1T,
    const float* __restrict__ b1, const __bf16* __restrict__ W2T,
    const float* __restrict__ b2, const __bf16* __restrict__ Cnew,
    __bf16* __restrict__ C)
{
  // buf b: Ast @ b*22528 (6K) | Wst @ b*22528+6144 (16K)
  // Hb @22528 (48K, post-L1) ; Snew overlay @0 (50688, post-L2)
  __shared__ __align__(16) char smem[71680];
  __bf16* Hb   = (__bf16*)(smem + 22528);
  __bf16* Snew = (__bf16*)smem;

  const int tid = threadIdx.x, l = tid & 63, w = tid >> 6;  // w 0..7
  const int m0 = blockIdx.x * 96;
  const int q4 = (l >> 4) * 4;

  f32x4 acc[6][2];
#pragma unroll
  for (int i = 0; i < 6; ++i)
#pragma unroll
    for (int j = 0; j < 2; ++j) acc[i][j] = (f32x4){0.f, 0.f, 0.f, 0.f};

  const __bf16* Sg = S + (size_t)(m0 + (tid >> 2)) * Dn + (tid & 3) * 8; // tid<384

  auto stageL1 = [&](int buf, int kt) {
    __bf16* Astb = (__bf16*)(smem + buf * 22528);
    __bf16* Wstb = (__bf16*)(smem + buf * 22528 + 6144);
    if (tid < 384) async_copy16(Sg + kt * 32, Astb + tid * 8);
#pragma unroll
    for (int r2 = 0; r2 < 2; ++r2) {
      const int ch = tid + r2 * 512, row = ch >> 2, kk = (ch & 3) * 8;
      async_copy16(W1T + (size_t)row * Dn + kt * 32 + kk, Wstb + ch * 8);
    }
  };

  // ---- layer 1 (double-buffered, 1 barrier/kt) ----
  stageL1(0, 0);
  __syncthreads();
  for (int kt = 0; kt < 8; ++kt) {
    if (kt < 7) stageL1((kt + 1) & 1, kt + 1);
    const __bf16* Astb = (const __bf16*)(smem + (kt & 1) * 22528);
    const __bf16* Wstb = Astb + 3072;
    bf16_8 bf[2];
#pragma unroll
    for (int j = 0; j < 2; ++j)
      bf[j] = *(const bf16_8*)(Wstb + (w * 32 + j * 16 + (l & 15)) * 32 + (l >> 4) * 8);
#pragma unroll
    for (int i = 0; i < 6; ++i) {
      bf16_8 af = *(const bf16_8*)(Astb + (i * 16 + (l & 15)) * 32 + (l >> 4) * 8);
#pragma unroll
      for (int j = 0; j < 2; ++j)
        acc[i][j] = __builtin_amdgcn_mfma_f32_16x16x32_bf16(af, bf[j], acc[i][j], 0, 0, 0);
    }
    __syncthreads();
  }

  // h = relu(acc + b1) -> pre-tiled LDS [kt][96][32] (overwrites L1 buf1)
#pragma unroll
  for (int j = 0; j < 2; ++j) {
    const int col = w * 32 + j * 16 + (l & 15);
    const float bj = b1[col];
    __bf16* hc = Hb + (col >> 5) * (96 * 32) + (col & 31);
#pragma unroll
    for (int i = 0; i < 6; ++i)
#pragma unroll
      for (int r = 0; r < 4; ++r) {
        const int row = i * 16 + q4 + r;
        hc[row * 32] = (__bf16)fmaxf(acc[i][j][r] + bj, 0.0f);
      }
  }
  __syncthreads();

  // ---- layer 2 (Wst @6144 single-buffered; Hb fully live) ----
#pragma unroll
  for (int i = 0; i < 6; ++i)
#pragma unroll
    for (int j = 0; j < 2; ++j) acc[i][j] = (f32x4){0.f, 0.f, 0.f, 0.f};
  __bf16* Wst = (__bf16*)(smem + 6144);
  for (int kt = 0; kt < 8; ++kt) {
#pragma unroll
    for (int r2 = 0; r2 < 2; ++r2) {
      const int ch = tid + r2 * 512, row = ch >> 2, kk = (ch & 3) * 8;
      async_copy16(W2T + (size_t)row * Dn + kt * 32 + kk, Wst + ch * 8);
    }
    __syncthreads();
    bf16_8 bf[2];
#pragma unroll
    for (int j = 0; j < 2; ++j)
      bf[j] = *(const bf16_8*)(Wst + (w * 32 + j * 16 + (l & 15)) * 32 + (l >> 4) * 8);
#pragma unroll
    for (int i = 0; i < 6; ++i) {
      bf16_8 af = *(const bf16_8*)(Hb + kt * (96 * 32) + (i * 16 + (l & 15)) * 32 + (l >> 4) * 8);
#pragma unroll
      for (int j = 0; j < 2; ++j)
        acc[i][j] = __builtin_amdgcn_mfma_f32_16x16x32_bf16(af, bf[j], acc[i][j], 0, 0, 0);
    }
    __syncthreads();
  }

  // snew (raw, +b2) -> LDS (stride 264)
#pragma unroll
  for (int j = 0; j < 2; ++j) {
    const int col = w * 32 + j * 16 + (l & 15);
    const float bj = b2[col];
#pragma unroll
    for (int i = 0; i < 6; ++i)
#pragma unroll
      for (int r = 0; r < 4; ++r) {
        const int row = i * 16 + q4 + r;
        Snew[row * 264 + col] = (__bf16)(acc[i][j][r] + bj);
      }
  }
  __syncthreads();

  // fused elementwise update: 16 ba-groups x 32 d-chunks = 512 tasks
  {
    const int ba = tid >> 5, dg = (tid & 31) * 8;
    const size_t gb = (size_t)(blockIdx.x * 16 + ba) * Dn + dg;
    bf16_8 cn8 = *(const bf16_8*)(Cnew + gb);
    float cn[8], m[8];
#pragma unroll
    for (int e = 0; e < 8; ++e) { cn[e] = (float)cn8[e]; m[e] = -3.402823466e38f; }
#pragma unroll
    for (int t = 0; t < Tn; ++t) {
      const int row = ba * 6 + t;
      bf16_8 sn8 = *(const bf16_8*)(Snew + row * 264 + dg);
      const size_t gs = (size_t)(m0 + row) * Dn + dg;
      bf16_8 s8 = *(const bf16_8*)(S + gs);
      bf16_8 o8;
#pragma unroll
      for (int e = 0; e < 8; ++e) {
        const float sn = (float)sn8[e] * cn[e];
        m[e] = fmaxf(m[e], sn);
        o8[e] = (__bf16)(kAlpha * (float)s8[e] + kBeta * sn);
      }
      *(bf16_8*)(S + gs) = o8;
    }
    bf16_8 c8 = *(const bf16_8*)(C + gb);
#pragma unroll
    for (int e = 0; e < 8; ++e)
      c8[e] = (__bf16)(kAlpha * (float)c8[e] + kBeta * m[e]);
    *(bf16_8*)(C + gb) = c8;
  }
}

// ---- fused decoder-2 + covariance, v3 (unchanged) --------------------------
__global__ __launch_bounds__(512, 4) void decoder2_fused(
    const __bf16* __restrict__ A, const __bf16* __restrict__ BT,
    const float* __restrict__ bias, float* __restrict__ out)
{
  __shared__ __align__(16) char smem[73728];
  float* mid = (float*)smem;                  // 32*241 floats, post-loop only

  const int tid = threadIdx.x, l = tid & 63, w = tid >> 6;  // w 0..7
  const int m0 = blockIdx.x * 64;
  const int q4 = (l >> 4) * 4;

  f32x4 acc[4][4];
#pragma unroll
  for (int i = 0; i < 4; ++i)
#pragma unroll
    for (int j = 0; j < 4; ++j) acc[i][j] = (f32x4){0.f, 0.f, 0.f, 0.f};

  const __bf16* Ag = A + (size_t)(m0 + (tid >> 2)) * Hn + (tid & 3) * 8;
  const __bf16* Bg[4];
#pragma unroll
  for (int r4 = 0; r4 < 4; ++r4) {
    const int ch = tid + r4 * 512;
    int row = ch >> 2; if (row > 400) row = 400;
    Bg[r4] = BT + (size_t)row * Hn + (ch & 3) * 8;
  }

  auto stage = [&](int buf, int kt) {
    const int ko = kt * 32;
    __bf16* base = (__bf16*)(smem + buf * 36864);
    if (tid < 256) async_copy16(Ag + ko, base + tid * 8);
    __bf16* Bl = base + 64 * 32;
#pragma unroll
    for (int r4 = 0; r4 < 4; ++r4)
      async_copy16(Bg[r4] + ko, Bl + (size_t)(tid + r4 * 512) * 8);
  };

  stage(0, 0);
  __syncthreads();
  int cur = 0;
  for (int kt = 0; kt < 16; ++kt) {
    if (kt < 15) stage(cur ^ 1, kt + 1);
    const __bf16* Asl = (const __bf16*)(smem + cur * 36864);
    const __bf16* Bsl = Asl + 64 * 32;
    bf16_8 af[4], bf[4];
#pragma unroll
    for (int j = 0; j < 4; ++j)
      bf[j] = *(const bf16_8*)(Bsl + (w * 64 + j * 16 + (l & 15)) * 32 + (l >> 4) * 8);
#pragma unroll
    for (int i = 0; i < 4; ++i)
      af[i] = *(const bf16_8*)(Asl + (i * 16 + (l & 15)) * 32 + (l >> 4) * 8);
#pragma unroll
    for (int i = 0; i < 4; ++i)
#pragma unroll
      for (int j = 0; j < 4; ++j)
        acc[i][j] = __builtin_amdgcn_mfma_f32_16x16x32_bf16(af[i], bf[j], acc[i][j], 0, 0, 0);
    __syncthreads();
    cur ^= 1;
  }

  float* cov = out + MR + (size_t)MR * 160;
  const int gc = w * 64 + (l & 15);
#pragma unroll
  for (int sub = 0; sub < 2; ++sub) {
#pragma unroll
    for (int ih = 0; ih < 2; ++ih) {
      const int i = sub * 2 + ih;
#pragma unroll
      for (int j = 0; j < 4; ++j) {
        const int c = gc + j * 16;
        if (c > 400) continue;
        const float bj = bias[c];
#pragma unroll
        for (int r = 0; r < 4; ++r) {
          const int lr = ih * 16 + q4 + r;
          const int gr = m0 + sub * 32 + lr;
          const float v = acc[i][j][r] + bj;
          if (c < 160)      out[(size_t)MR + (size_t)gr * 160 + c] = v;
          else if (c < 400) mid[lr * 241 + (c - 160)] = v;
          else              out[gr] = v;
        }
      }
    }
    __syncthreads();
#pragma unroll
    for (int p = 0; p < 5; ++p) {
      const int q = p * 512 + tid;
      const int r32 = q / 80, j = q - r32 * 80;
      const int gr = m0 + sub * 32 + r32;
      const float av = mid[r32 * 241 + j];
      const float bv = mid[r32 * 241 + 80 + j];
      const float cv = mid[r32 * 241 + 160 + j];
      const float eb = __expf(bv), ebn = __expf(-bv);
      const float sh = 0.5f * (eb - ebn), ch = 0.5f * (eb + ebn);
      const float ea = __expf(av), ean = __expf(-av), ec = __expf(cv);
      f32x4 c4 = { ea * ch * ec, sh * ec, sh * ec, ean * ch * ec };
      *(f32x4*)(cov + (size_t)gr * 320 + 4 * j) = c4;
    }
    if (sub == 0) __syncthreads();
  }
}

// ---- weight transpose + bf16 convert ---------------------------------------
__global__ __launch_bounds__(256) void transpose_bf16(
    const float* __restrict__ W, __bf16* __restrict__ WT, int K, int N)
{
  __shared__ float t[32][33];
  const int b  = blockIdx.z;
  const int tx = threadIdx.x, ty = threadIdx.y;
  const int k0 = blockIdx.y * 32, n0 = blockIdx.x * 32;
  const float* Wb  = W  + (size_t)b * K * N;
  __bf16*      WTb = WT + (size_t)b * N * K;
#pragma unroll
  for (int r = 0; r < 4; ++r) {
    int kk = k0 + ty + r * 8;
    if (kk < K && n0 + tx < N) t[ty + r * 8][tx] = Wb[(size_t)kk * N + n0 + tx];
  }
  __syncthreads();
#pragma unroll
  for (int r = 0; r < 4; ++r) {
    int nn = n0 + ty + r * 8;
    if (nn < N && k0 + tx < K)
      WTb[(size_t)nn * K + k0 + tx] = (__bf16)t[tx][ty + r * 8];
  }
}

__global__ __launch_bounds__(256) void convert_bf16(
    const float* __restrict__ in, __bf16* __restrict__ out, int n)
{
  int i = blockIdx.x * 256 + threadIdx.x;
  if (i < n) out[i] = (__bf16)in[i];
}

// ---- iter-0 elementwise (init folded) --------------------------------------
__global__ __launch_bounds__(256) void ew_update0(
    const float* __restrict__ anchor, const float* __restrict__ fe,
    const float* __restrict__ snewsm, const __bf16* __restrict__ cnew,
    __bf16* __restrict__ s, __bf16* __restrict__ c)
{
  int q = blockIdx.x * 256 + threadIdx.x;
  if (q >= BA * 32) return;
  int ba = q >> 5;
  int dg = (q & 31) * 8;
  bf16_8 cn8 = *(const bf16_8*)(cnew + (size_t)ba * Dn + dg);
  float cn[8], m[8];
#pragma unroll
  for (int e = 0; e < 8; ++e) { cn[e] = (float)cn8[e]; m[e] = -3.402823466e38f; }
  size_t base = (size_t)ba * Tn * Dn + dg;
#pragma unroll
  for (int t = 0; t < Tn; ++t) {
    bf16_8 o8;
#pragma unroll
    for (int e = 0; e < 8; ++e) {
      float sn = snewsm[t * Dn + dg + e] * cn[e];
      m[e] = fmaxf(m[e], sn);
      o8[e] = (__bf16)(kAlpha * anchor[t * Dn + dg + e] + kBeta * sn);
    }
    *(bf16_8*)(s + base + t * Dn) = o8;
  }
  bf16_8 c8;
#pragma unroll
  for (int e = 0; e < 8; ++e)
    c8[e] = (__bf16)(kAlpha * fe[(size_t)ba * Dn + dg + e] + kBeta * m[e]);
  *(bf16_8*)(c + (size_t)ba * Dn + dg) = c8;
}

// ---------------------------------------------------------------------------
extern "C" void kernel_launch(void* const* d_in, const int* in_sizes, int n_in,
                              void* d_out, int out_size, void* d_ws, size_t ws_size,
                              hipStream_t stream) {
  const float* fe     = (const float*)d_in[0];
  const float* anchor = (const float*)d_in[1];
  const float* sW1 = (const float*)d_in[2];
  const float* sb1 = (const float*)d_in[3];
  const float* sW2 = (const float*)d_in[4];
  const float* sb2 = (const float*)d_in[5];
  const float* cW1 = (const float*)d_in[6];
  const float* cb1 = (const float*)d_in[7];
  const float* cW2 = (const float*)d_in[8];
  const float* cb2 = (const float*)d_in[9];
  const float* dW1 = (const float*)d_in[10];
  const float* db1 = (const float*)d_in[11];
  const float* dW2 = (const float*)d_in[12];
  const float* db2 = (const float*)d_in[13];
  float* out = (float*)d_out;

  // ---- workspace layout (bytes), total ~91.4 MB ----
  char* p = (char*)d_ws;
  __bf16* s_bf    = (__bf16*)(p + 0);            // 25,165,824
  __bf16* hd_bf   = (__bf16*)(p + 25165824);     // 50,331,648
  __bf16* c_bf    = (__bf16*)(p + 75497472);     //  4,194,304
  __bf16* cnew_bf = (__bf16*)(p + 79691776);     //  4,194,304
  __bf16* fe_bf   = (__bf16*)(p + 83886080);     //  4,194,304
  __bf16* sWT1    = (__bf16*)(p + 88080384);     //    655,360 each
  __bf16* sWT2    = (__bf16*)(p + 88735744);
  __bf16* cWT1    = (__bf16*)(p + 89391104);
  __bf16* cWT2    = (__bf16*)(p + 90046464);
  __bf16* dWT1    = (__bf16*)(p + 90701824);     //    262,144
  __bf16* dWT2    = (__bf16*)(p + 90963968);     //    410,624
  __bf16* anc_bf  = (__bf16*)(p + 91374592);     //      3,072
  __bf16* hsm_bf  = (__bf16*)(p + 91377664);     //      3,072
  float*  snewsm_f= (float* )(p + 91380736);     //      6,144

  auto gemm = [&](const __bf16* A, const __bf16* BT, const float* b, void* C,
                  int M, int N, int K, bool relu, bool outbf) {
    dim3 grid((N + 127) / 128, (M + 127) / 128);
    if (relu) {
      if (outbf) gemm_mfma<true,  true ><<<grid, 256, 0, stream>>>(A, BT, b, C, M, N, K);
      else       gemm_mfma<true,  false><<<grid, 256, 0, stream>>>(A, BT, b, C, M, N, K);
    } else {
      if (outbf) gemm_mfma<false, true ><<<grid, 256, 0, stream>>>(A, BT, b, C, M, N, K);
      else       gemm_mfma<false, false><<<grid, 256, 0, stream>>>(A, BT, b, C, M, N, K);
    }
  };

  // ---- weight prep ----
  {
    dim3 blk(32, 8);
    dim3 g88(8, 8, NBn);
    transpose_bf16<<<g88, blk, 0, stream>>>(sW1, sWT1, Dn, Dn);
    transpose_bf16<<<g88, blk, 0, stream>>>(sW2, sWT2, Dn, Dn);
    transpose_bf16<<<g88, blk, 0, stream>>>(cW1, cWT1, Dn, Dn);
    transpose_bf16<<<g88, blk, 0, stream>>>(cW2, cWT2, Dn, Dn);
    transpose_bf16<<<dim3(16, 8, 1), blk, 0, stream>>>(dW1, dWT1, Dn, Hn);
    transpose_bf16<<<dim3(13, 16, 1), blk, 0, stream>>>(dW2, dWT2, Hn, OUTn);
  }
  convert_bf16<<<(BA * Dn + 255) / 256, 256, 0, stream>>>(fe, fe_bf, BA * Dn);
  convert_bf16<<<(Tn * Dn + 255) / 256, 256, 0, stream>>>(anchor, anc_bf, Tn * Dn);

  const size_t WKK = (size_t)Dn * Dn;

  // ---- iteration 0 (s-branch on 6 anchor rows; c-branch fused MLP) ----
  gemm(anc_bf, sWT1, sb1, hsm_bf,   Tn, Dn, Dn, true,  true);
  gemm(hsm_bf, sWT2, sb2, snewsm_f, Tn, Dn, Dn, false, false);
  mlp2_c<<<BA / 32, 512, 0, stream>>>(fe_bf, cWT1, cb1, cWT2, cb2, cnew_bf);
  ew_update0<<<(BA * 32 + 255) / 256, 256, 0, stream>>>(anchor, fe, snewsm_f,
                                                        cnew_bf, s_bf, c_bf);

  // ---- iterations 1..4: two fused kernels each ----
  for (int i = 1; i < NBn; ++i) {
    mlp2_c<<<BA / 32, 512, 0, stream>>>(c_bf, cWT1 + i * WKK, cb1 + i * Dn,
                                        cWT2 + i * WKK, cb2 + i * Dn, cnew_bf);
    mlp2_s<<<MR / 96, 512, 0, stream>>>(s_bf, sWT1 + i * WKK, sb1 + i * Dn,
                                        sWT2 + i * WKK, sb2 + i * Dn,
                                        cnew_bf, c_bf);
  }

  // ---- decoder ----
  gemm(s_bf, dWT1, db1, hd_bf, MR, Hn, Dn, true, true);
  decoder2_fused<<<MR / 64, 512, 0, stream>>>(hd_bf, dWT2, db2, out);
}

// Round 3
// 374.363 us; speedup vs baseline: 1.3405x; 1.0507x over previous
//
#include <hip/hip_runtime.h>
#include <math.h>

// ---------------------------------------------------------------------------
// Round 8: fuse c-MLP into mlp2_s (iterations 1..4).
//  - mlp2_cs: per block (16 ba-groups / 96 s-rows): compute cnew=mlp_c(c)
//    locally (Hc/CnewL in the 26KB dead LDS zone), hold cn8 in registers,
//    then the s-MLP + update as before. cnew never touches HBM; 4 dispatches
//    and 32MB of HBM round-trip removed. LDS stays 70K -> 2 blocks/CU.
//  - mlp2_c kept only for iteration 0 (input = fe).
//  - decoder2_fused v3 unchanged (70us, ~3x above its HBM floor; parked).
// ---------------------------------------------------------------------------

constexpr int Tn  = 6;
constexpr int Dn  = 256;
constexpr int Hn  = 512;
constexpr int NBn = 5;
constexpr int OUTn = 401;
constexpr int BA  = 8192;
constexpr int MR  = 49152;
constexpr float kAlpha = 0.5f;
constexpr float kBeta  = 0.5f;

typedef __bf16 bf16_8 __attribute__((ext_vector_type(8)));
typedef float  f32x4  __attribute__((ext_vector_type(4)));

__device__ __forceinline__ void async_copy16(const __bf16* g, __bf16* l) {
  __builtin_amdgcn_global_load_lds(
      (const __attribute__((address_space(1))) void*)g,
      (__attribute__((address_space(3))) void*)l, 16, 0, 0);
}

// ---- generic GEMM (anchor GEMMs + decoder-1), double-buffered --------------
template<bool RELU, bool OUT_BF16>
__global__ __launch_bounds__(256) void gemm_mfma(
    const __bf16* __restrict__ A, const __bf16* __restrict__ BT,
    const float* __restrict__ bias, void* __restrict__ Cout,
    int M, int N, int K)
{
  __shared__ __align__(16) char smem[34816];

  const int tid = threadIdx.x;
  const int l   = tid & 63;
  const int w   = tid >> 6;
  const int wm  = w >> 1, wn = w & 1;

  const int GX = gridDim.x;
  const int total = GX * gridDim.y;
  const int L = blockIdx.y * GX + blockIdx.x;
  const int xcd = L & 7, pos = L >> 3;
  const int base = total >> 3, rem = total & 7;
  const int start = xcd * base + (xcd < rem ? xcd : rem);
  const int TL = start + pos;
  const int my = TL / GX;
  const int nx = TL - my * GX;
  const int m0 = my * 128;
  const int n0 = nx * 128;

  const int lrow = l >> 2;
  const int lk   = (l & 3) * 8;
  int ar0 = m0 + w * 32 + lrow;        if (ar0 > M - 1) ar0 = M - 1;
  int ar1 = m0 + w * 32 + 16 + lrow;   if (ar1 > M - 1) ar1 = M - 1;
  int br0 = n0 + w * 32 + lrow;        if (br0 > N - 1) br0 = N - 1;
  int br1 = n0 + w * 32 + 16 + lrow;   if (br1 > N - 1) br1 = N - 1;
  const __bf16* Ag0 = A  + (size_t)ar0 * K + lk;
  const __bf16* Ag1 = A  + (size_t)ar1 * K + lk;
  const __bf16* Bg0 = BT + (size_t)br0 * K + lk;
  const __bf16* Bg1 = BT + (size_t)br1 * K + lk;

  f32x4 acc[4][4];
#pragma unroll
  for (int i = 0; i < 4; ++i)
#pragma unroll
    for (int j = 0; j < 4; ++j) acc[i][j] = (f32x4){0.f, 0.f, 0.f, 0.f};

  auto stage = [&](int buf, int ko) {
    __bf16* As = (__bf16*)(smem + buf * 16384);
    __bf16* Bs = As + 4096;
    async_copy16(Ag0 + ko, As + w * 1024);
    async_copy16(Ag1 + ko, As + w * 1024 + 512);
    async_copy16(Bg0 + ko, Bs + w * 1024);
    async_copy16(Bg1 + ko, Bs + w * 1024 + 512);
  };

  const int kIters = K >> 5;
  stage(0, 0);
  __syncthreads();
  for (int kt = 0; kt < kIters; ++kt) {
    if (kt + 1 < kIters) stage((kt + 1) & 1, (kt + 1) * 32);
    const __bf16* As = (const __bf16*)(smem + (kt & 1) * 16384);
    const __bf16* Bs = As + 4096;
    const __bf16* ap = As + (wm * 64 + (l & 15)) * 32 + (l >> 4) * 8;
    const __bf16* bp = Bs + (wn * 64 + (l & 15)) * 32 + (l >> 4) * 8;

    bf16_8 af[4], bf[4];
#pragma unroll
    for (int i = 0; i < 4; ++i) af[i] = *(const bf16_8*)(ap + i * 16 * 32);
#pragma unroll
    for (int j = 0; j < 4; ++j) bf[j] = *(const bf16_8*)(bp + j * 16 * 32);
#pragma unroll
    for (int i = 0; i < 4; ++i)
#pragma unroll
      for (int j = 0; j < 4; ++j)
        acc[i][j] = __builtin_amdgcn_mfma_f32_16x16x32_bf16(af[i], bf[j], acc[i][j], 0, 0, 0);
    __syncthreads();
  }

  const int colb = n0 + wn * 64 + (l & 15);
  const int rowb = m0 + wm * 64 + (l >> 4) * 4;

  if (OUT_BF16) {
    __bf16* Cs = (__bf16*)smem;
    const int lrb = wm * 64 + (l >> 4) * 4;
    const int lcb = wn * 64 + (l & 15);
#pragma unroll
    for (int j = 0; j < 4; ++j) {
      const float bj = bias[colb + j * 16];
#pragma unroll
      for (int i = 0; i < 4; ++i) {
#pragma unroll
        for (int r = 0; r < 4; ++r) {
          float v = acc[i][j][r] + bj;
          if (RELU) v = fmaxf(v, 0.0f);
          Cs[(lrb + i * 16 + r) * 136 + lcb + j * 16] = (__bf16)v;
        }
      }
    }
    __syncthreads();
    __bf16* Cg = (__bf16*)Cout;
#pragma unroll
    for (int it = 0; it < 8; ++it) {
      const int idx = it * 256 + tid;
      const int row = idx >> 4, c16 = idx & 15;
      const int gr = m0 + row;
      if (gr < M) {
        uint4 v = *(const uint4*)(Cs + row * 136 + c16 * 8);
        *(uint4*)(Cg + (size_t)gr * N + n0 + c16 * 8) = v;
      }
    }
  } else {
#pragma unroll
    for (int j = 0; j < 4; ++j) {
      const int gc = colb + j * 16;
      if (gc >= N) continue;
      const float bj = bias[gc];
#pragma unroll
      for (int i = 0; i < 4; ++i) {
        const int gr0 = rowb + i * 16;
#pragma unroll
        for (int r = 0; r < 4; ++r) {
          const int gr = gr0 + r;
          if (gr >= M) continue;
          float v = acc[i][j][r] + bj;
          if (RELU) v = fmaxf(v, 0.0f);
          ((float*)Cout)[(size_t)gr * N + gc] = v;
        }
      }
    }
  }
}

// ---- fused 2-layer c-MLP (iteration 0 only) --------------------------------
__global__ __launch_bounds__(512) void mlp2_c(
    const __bf16* __restrict__ X, const __bf16* __restrict__ W1T,
    const float* __restrict__ b1, const __bf16* __restrict__ W2T,
    const float* __restrict__ b2, __bf16* __restrict__ Out)
{
  // Ast bufs @0,2048 (2K) | Wst bufs @4096,20480 (16K) | Hb @36864 (16K)
  __shared__ __align__(16) char smem[53248];
  __bf16* Hb = (__bf16*)(smem + 36864);

  const int tid = threadIdx.x, l = tid & 63, w = tid >> 6;  // w 0..7
  const int m0 = blockIdx.x * 32;
  const int q4 = (l >> 4) * 4;

  f32x4 acc[2][2];
#pragma unroll
  for (int i = 0; i < 2; ++i)
#pragma unroll
    for (int j = 0; j < 2; ++j) acc[i][j] = (f32x4){0.f, 0.f, 0.f, 0.f};

  const __bf16* Xg = X + (size_t)(m0 + (tid >> 2)) * Dn + (tid & 3) * 8; // tid<128

  auto stageA = [&](int buf, int kt) {
    if (tid < 128)
      async_copy16(Xg + kt * 32, (__bf16*)(smem + buf * 2048) + tid * 8);
  };
  auto stageW = [&](const __bf16* WT, int buf, int kt) {
    __bf16* Wstb = (__bf16*)(smem + 4096 + buf * 16384);
#pragma unroll
    for (int r2 = 0; r2 < 2; ++r2) {
      const int ch = tid + r2 * 512, row = ch >> 2, kk = (ch & 3) * 8;
      async_copy16(WT + (size_t)row * Dn + kt * 32 + kk, Wstb + ch * 8);
    }
  };

  // ---- layer 1 ----
  stageA(0, 0); stageW(W1T, 0, 0);
  __syncthreads();
  for (int kt = 0; kt < 8; ++kt) {
    if (kt < 7) { stageA((kt + 1) & 1, kt + 1); stageW(W1T, (kt + 1) & 1, kt + 1); }
    const __bf16* Astb = (const __bf16*)(smem + (kt & 1) * 2048);
    const __bf16* Wstb = (const __bf16*)(smem + 4096 + (kt & 1) * 16384);
    bf16_8 bf[2];
#pragma unroll
    for (int j = 0; j < 2; ++j)
      bf[j] = *(const bf16_8*)(Wstb + (w * 32 + j * 16 + (l & 15)) * 32 + (l >> 4) * 8);
#pragma unroll
    for (int i = 0; i < 2; ++i) {
      bf16_8 af = *(const bf16_8*)(Astb + (i * 16 + (l & 15)) * 32 + (l >> 4) * 8);
#pragma unroll
      for (int j = 0; j < 2; ++j)
        acc[i][j] = __builtin_amdgcn_mfma_f32_16x16x32_bf16(af, bf[j], acc[i][j], 0, 0, 0);
    }
    __syncthreads();
  }

  // h = relu(acc + b1) -> pre-tiled LDS [kt][32][32]
#pragma unroll
  for (int j = 0; j < 2; ++j) {
    const int col = w * 32 + j * 16 + (l & 15);
    const float bj = b1[col];
    __bf16* hc = Hb + (col >> 5) * 1024 + (col & 31);
#pragma unroll
    for (int i = 0; i < 2; ++i)
#pragma unroll
      for (int r = 0; r < 4; ++r) {
        const int row = i * 16 + q4 + r;
        hc[row * 32] = (__bf16)fmaxf(acc[i][j][r] + bj, 0.0f);
      }
  }
  __syncthreads();

  // ---- layer 2 ----
#pragma unroll
  for (int i = 0; i < 2; ++i)
#pragma unroll
    for (int j = 0; j < 2; ++j) acc[i][j] = (f32x4){0.f, 0.f, 0.f, 0.f};
  stageW(W2T, 0, 0);
  __syncthreads();
  for (int kt = 0; kt < 8; ++kt) {
    if (kt < 7) stageW(W2T, (kt + 1) & 1, kt + 1);
    const __bf16* Wstb = (const __bf16*)(smem + 4096 + (kt & 1) * 16384);
    bf16_8 bf[2];
#pragma unroll
    for (int j = 0; j < 2; ++j)
      bf[j] = *(const bf16_8*)(Wstb + (w * 32 + j * 16 + (l & 15)) * 32 + (l >> 4) * 8);
#pragma unroll
    for (int i = 0; i < 2; ++i) {
      bf16_8 af = *(const bf16_8*)(Hb + kt * 1024 + (i * 16 + (l & 15)) * 32 + (l >> 4) * 8);
#pragma unroll
      for (int j = 0; j < 2; ++j)
        acc[i][j] = __builtin_amdgcn_mfma_f32_16x16x32_bf16(af, bf[j], acc[i][j], 0, 0, 0);
    }
    __syncthreads();
  }

#pragma unroll
  for (int j = 0; j < 2; ++j) {
    const int col = w * 32 + j * 16 + (l & 15);
    const float bj = b2[col];
#pragma unroll
    for (int i = 0; i < 2; ++i)
#pragma unroll
      for (int r = 0; r < 4; ++r) {
        const int row = i * 16 + q4 + r;
        Out[(size_t)(m0 + row) * Dn + col] = (__bf16)(acc[i][j][r] + bj);
      }
  }
}

// ---- fused c-MLP + s-MLP + elementwise update (iterations 1..4) ------------
// Per block: 16 ba-groups (16 c rows, 96 s rows). cnew computed locally,
// carried in registers (cn8); never touches HBM.
__global__ __launch_bounds__(512) void mlp2_cs(
    __bf16* __restrict__ S,
    const __bf16* __restrict__ sW1T, const float* __restrict__ sb1,
    const __bf16* __restrict__ sW2T, const float* __restrict__ sb2,
    const __bf16* __restrict__ cW1T, const float* __restrict__ cb1,
    const __bf16* __restrict__ cW2T, const float* __restrict__ cb2,
    __bf16* __restrict__ C)
{
  // buf b: Ast @ b*22528 (6K) | Wst @ b*22528+6144 (16K)   [phases C-L1, S-L1]
  // Hc @45056 (8K), CnewL @53248 (8.4K)                    [phase C only]
  // Hb @22528 (48K, post-S-L1) ; Snew overlay @0 (50.7K, post-S-L2)
  __shared__ __align__(16) char smem[71680];
  __bf16* Hb    = (__bf16*)(smem + 22528);
  __bf16* Snew  = (__bf16*)smem;
  __bf16* Hc    = (__bf16*)(smem + 45056);
  __bf16* CnewL = (__bf16*)(smem + 53248);

  const int tid = threadIdx.x, l = tid & 63, w = tid >> 6;  // w 0..7
  const int m0  = blockIdx.x * 96;
  const int ba0 = blockIdx.x * 16;
  const int q4  = (l >> 4) * 4;

  // ===================== Phase C: cnew = mlp_c(C[16 rows]) ==================
  {
    f32x4 ac[2];
    ac[0] = (f32x4){0.f, 0.f, 0.f, 0.f};
    ac[1] = (f32x4){0.f, 0.f, 0.f, 0.f};

    const __bf16* Cg = C + (size_t)(ba0 + (tid >> 2)) * Dn + (tid & 3) * 8; // tid<64

    // ---- c layer 1 (dbuf) ----
    auto stageC1 = [&](int buf, int kt) {
      __bf16* Astb = (__bf16*)(smem + buf * 22528);
      __bf16* Wstb = Astb + 3072;
      if (tid < 64) async_copy16(Cg + kt * 32, Astb + tid * 8);
#pragma unroll
      for (int r2 = 0; r2 < 2; ++r2) {
        const int ch = tid + r2 * 512, row = ch >> 2, kk = (ch & 3) * 8;
        async_copy16(cW1T + (size_t)row * Dn + kt * 32 + kk, Wstb + ch * 8);
      }
    };
    stageC1(0, 0);
    __syncthreads();
    for (int kt = 0; kt < 8; ++kt) {
      if (kt < 7) stageC1((kt + 1) & 1, kt + 1);
      const __bf16* Astb = (const __bf16*)(smem + (kt & 1) * 22528);
      const __bf16* Wstb = Astb + 3072;
      bf16_8 bf[2];
#pragma unroll
      for (int j = 0; j < 2; ++j)
        bf[j] = *(const bf16_8*)(Wstb + (w * 32 + j * 16 + (l & 15)) * 32 + (l >> 4) * 8);
      bf16_8 af = *(const bf16_8*)(Astb + (l & 15) * 32 + (l >> 4) * 8);
#pragma unroll
      for (int j = 0; j < 2; ++j)
        ac[j] = __builtin_amdgcn_mfma_f32_16x16x32_bf16(af, bf[j], ac[j], 0, 0, 0);
      __syncthreads();
    }

    // hc = relu(ac + cb1) -> pre-tiled [kt][16][32] @ Hc
#pragma unroll
    for (int j = 0; j < 2; ++j) {
      const int col = w * 32 + j * 16 + (l & 15);
      const float bj = cb1[col];
      __bf16* hc = Hc + (col >> 5) * 512 + (col & 31);
#pragma unroll
      for (int r = 0; r < 4; ++r)
        hc[(q4 + r) * 32] = (__bf16)fmaxf(ac[j][r] + bj, 0.0f);
    }
    __syncthreads();

    // ---- c layer 2 (dbuf W only) ----
    ac[0] = (f32x4){0.f, 0.f, 0.f, 0.f};
    ac[1] = (f32x4){0.f, 0.f, 0.f, 0.f};
    auto stageC2 = [&](int buf, int kt) {
      __bf16* Wstb = (__bf16*)(smem + buf * 22528 + 6144);
#pragma unroll
      for (int r2 = 0; r2 < 2; ++r2) {
        const int ch = tid + r2 * 512, row = ch >> 2, kk = (ch & 3) * 8;
        async_copy16(cW2T + (size_t)row * Dn + kt * 32 + kk, Wstb + ch * 8);
      }
    };
    stageC2(0, 0);
    __syncthreads();
    for (int kt = 0; kt < 8; ++kt) {
      if (kt < 7) stageC2((kt + 1) & 1, kt + 1);
      const __bf16* Wstb = (const __bf16*)(smem + (kt & 1) * 22528 + 6144);
      bf16_8 bf[2];
#pragma unroll
      for (int j = 0; j < 2; ++j)
        bf[j] = *(const bf16_8*)(Wstb + (w * 32 + j * 16 + (l & 15)) * 32 + (l >> 4) * 8);
      bf16_8 af = *(const bf16_8*)(Hc + kt * 512 + (l & 15) * 32 + (l >> 4) * 8);
#pragma unroll
      for (int j = 0; j < 2; ++j)
        ac[j] = __builtin_amdgcn_mfma_f32_16x16x32_bf16(af, bf[j], ac[j], 0, 0, 0);
      __syncthreads();
    }

    // cnew (bf16, +cb2) -> CnewL [16][264]
#pragma unroll
    for (int j = 0; j < 2; ++j) {
      const int col = w * 32 + j * 16 + (l & 15);
      const float bj = cb2[col];
#pragma unroll
      for (int r = 0; r < 4; ++r)
        CnewL[(q4 + r) * 264 + col] = (__bf16)(ac[j][r] + bj);
    }
    __syncthreads();
  }

  // each thread grabs its update-slice of cnew into registers
  bf16_8 cn8 = *(const bf16_8*)(CnewL + (tid >> 5) * 264 + (tid & 31) * 8);

  // ===================== Phase S: s-MLP + update ============================
  f32x4 acc[6][2];
#pragma unroll
  for (int i = 0; i < 6; ++i)
#pragma unroll
    for (int j = 0; j < 2; ++j) acc[i][j] = (f32x4){0.f, 0.f, 0.f, 0.f};

  const __bf16* Sg = S + (size_t)(m0 + (tid >> 2)) * Dn + (tid & 3) * 8; // tid<384

  auto stageL1 = [&](int buf, int kt) {
    __bf16* Astb = (__bf16*)(smem + buf * 22528);
    __bf16* Wstb = (__bf16*)(smem + buf * 22528 + 6144);
    if (tid < 384) async_copy16(Sg + kt * 32, Astb + tid * 8);
#pragma unroll
    for (int r2 = 0; r2 < 2; ++r2) {
      const int ch = tid + r2 * 512, row = ch >> 2, kk = (ch & 3) * 8;
      async_copy16(sW1T + (size_t)row * Dn + kt * 32 + kk, Wstb + ch * 8);
    }
  };

  // ---- s layer 1 (double-buffered, 1 barrier/kt) ----
  stageL1(0, 0);
  __syncthreads();
  for (int kt = 0; kt < 8; ++kt) {
    if (kt < 7) stageL1((kt + 1) & 1, kt + 1);
    const __bf16* Astb = (const __bf16*)(smem + (kt & 1) * 22528);
    const __bf16* Wstb = Astb + 3072;
    bf16_8 bf[2];
#pragma unroll
    for (int j = 0; j < 2; ++j)
      bf[j] = *(const bf16_8*)(Wstb + (w * 32 + j * 16 + (l & 15)) * 32 + (l >> 4) * 8);
#pragma unroll
    for (int i = 0; i < 6; ++i) {
      bf16_8 af = *(const bf16_8*)(Astb + (i * 16 + (l & 15)) * 32 + (l >> 4) * 8);
#pragma unroll
      for (int j = 0; j < 2; ++j)
        acc[i][j] = __builtin_amdgcn_mfma_f32_16x16x32_bf16(af, bf[j], acc[i][j], 0, 0, 0);
    }
    __syncthreads();
  }

  // h = relu(acc + sb1) -> pre-tiled LDS [kt][96][32] (clobbers Hc/CnewL too)
#pragma unroll
  for (int j = 0; j < 2; ++j) {
    const int col = w * 32 + j * 16 + (l & 15);
    const float bj = sb1[col];
    __bf16* hc = Hb + (col >> 5) * (96 * 32) + (col & 31);
#pragma unroll
    for (int i = 0; i < 6; ++i)
#pragma unroll
      for (int r = 0; r < 4; ++r) {
        const int row = i * 16 + q4 + r;
        hc[row * 32] = (__bf16)fmaxf(acc[i][j][r] + bj, 0.0f);
      }
  }
  __syncthreads();

  // ---- s layer 2 (Wst @6144 single-buffered; Hb fully live) ----
#pragma unroll
  for (int i = 0; i < 6; ++i)
#pragma unroll
    for (int j = 0; j < 2; ++j) acc[i][j] = (f32x4){0.f, 0.f, 0.f, 0.f};
  __bf16* Wst = (__bf16*)(smem + 6144);
  for (int kt = 0; kt < 8; ++kt) {
#pragma unroll
    for (int r2 = 0; r2 < 2; ++r2) {
      const int ch = tid + r2 * 512, row = ch >> 2, kk = (ch & 3) * 8;
      async_copy16(sW2T + (size_t)row * Dn + kt * 32 + kk, Wst + ch * 8);
    }
    __syncthreads();
    bf16_8 bf[2];
#pragma unroll
    for (int j = 0; j < 2; ++j)
      bf[j] = *(const bf16_8*)(Wst + (w * 32 + j * 16 + (l & 15)) * 32 + (l >> 4) * 8);
#pragma unroll
    for (int i = 0; i < 6; ++i) {
      bf16_8 af = *(const bf16_8*)(Hb + kt * (96 * 32) + (i * 16 + (l & 15)) * 32 + (l >> 4) * 8);
#pragma unroll
      for (int j = 0; j < 2; ++j)
        acc[i][j] = __builtin_amdgcn_mfma_f32_16x16x32_bf16(af, bf[j], acc[i][j], 0, 0, 0);
    }
    __syncthreads();
  }

  // snew (raw, +sb2) -> LDS (stride 264)
#pragma unroll
  for (int j = 0; j < 2; ++j) {
    const int col = w * 32 + j * 16 + (l & 15);
    const float bj = sb2[col];
#pragma unroll
    for (int i = 0; i < 6; ++i)
#pragma unroll
      for (int r = 0; r < 4; ++r) {
        const int row = i * 16 + q4 + r;
        Snew[row * 264 + col] = (__bf16)(acc[i][j][r] + bj);
      }
  }
  __syncthreads();

  // fused elementwise update (cnew from registers)
  {
    const int ba = tid >> 5, dg = (tid & 31) * 8;
    const size_t gb = (size_t)(ba0 + ba) * Dn + dg;
    float cn[8], m[8];
#pragma unroll
    for (int e = 0; e < 8; ++e) { cn[e] = (float)cn8[e]; m[e] = -3.402823466e38f; }
#pragma unroll
    for (int t = 0; t < Tn; ++t) {
      const int row = ba * 6 + t;
      bf16_8 sn8 = *(const bf16_8*)(Snew + row * 264 + dg);
      const size_t gs = (size_t)(m0 + row) * Dn + dg;
      bf16_8 s8 = *(const bf16_8*)(S + gs);
      bf16_8 o8;
#pragma unroll
      for (int e = 0; e < 8; ++e) {
        const float sn = (float)sn8[e] * cn[e];
        m[e] = fmaxf(m[e], sn);
        o8[e] = (__bf16)(kAlpha * (float)s8[e] + kBeta * sn);
      }
      *(bf16_8*)(S + gs) = o8;
    }
    bf16_8 c8 = *(const bf16_8*)(C + gb);
#pragma unroll
    for (int e = 0; e < 8; ++e)
      c8[e] = (__bf16)(kAlpha * (float)c8[e] + kBeta * m[e]);
    *(bf16_8*)(C + gb) = c8;
  }
}

// ---- fused decoder-2 + covariance, v3 (unchanged) --------------------------
__global__ __launch_bounds__(512, 4) void decoder2_fused(
    const __bf16* __restrict__ A, const __bf16* __restrict__ BT,
    const float* __restrict__ bias, float* __restrict__ out)
{
  __shared__ __align__(16) char smem[73728];
  float* mid = (float*)smem;

  const int tid = threadIdx.x, l = tid & 63, w = tid >> 6;  // w 0..7
  const int m0 = blockIdx.x * 64;
  const int q4 = (l >> 4) * 4;

  f32x4 acc[4][4];
#pragma unroll
  for (int i = 0; i < 4; ++i)
#pragma unroll
    for (int j = 0; j < 4; ++j) acc[i][j] = (f32x4){0.f, 0.f, 0.f, 0.f};

  const __bf16* Ag = A + (size_t)(m0 + (tid >> 2)) * Hn + (tid & 3) * 8;
  const __bf16* Bg[4];
#pragma unroll
  for (int r4 = 0; r4 < 4; ++r4) {
    const int ch = tid + r4 * 512;
    int row = ch >> 2; if (row > 400) row = 400;
    Bg[r4] = BT + (size_t)row * Hn + (ch & 3) * 8;
  }

  auto stage = [&](int buf, int kt) {
    const int ko = kt * 32;
    __bf16* base = (__bf16*)(smem + buf * 36864);
    if (tid < 256) async_copy16(Ag + ko, base + tid * 8);
    __bf16* Bl = base + 64 * 32;
#pragma unroll
    for (int r4 = 0; r4 < 4; ++r4)
      async_copy16(Bg[r4] + ko, Bl + (size_t)(tid + r4 * 512) * 8);
  };

  stage(0, 0);
  __syncthreads();
  int cur = 0;
  for (int kt = 0; kt < 16; ++kt) {
    if (kt < 15) stage(cur ^ 1, kt + 1);
    const __bf16* Asl = (const __bf16*)(smem + cur * 36864);
    const __bf16* Bsl = Asl + 64 * 32;
    bf16_8 af[4], bf[4];
#pragma unroll
    for (int j = 0; j < 4; ++j)
      bf[j] = *(const bf16_8*)(Bsl + (w * 64 + j * 16 + (l & 15)) * 32 + (l >> 4) * 8);
#pragma unroll
    for (int i = 0; i < 4; ++i)
      af[i] = *(const bf16_8*)(Asl + (i * 16 + (l & 15)) * 32 + (l >> 4) * 8);
#pragma unroll
    for (int i = 0; i < 4; ++i)
#pragma unroll
      for (int j = 0; j < 4; ++j)
        acc[i][j] = __builtin_amdgcn_mfma_f32_16x16x32_bf16(af[i], bf[j], acc[i][j], 0, 0, 0);
    __syncthreads();
    cur ^= 1;
  }

  float* cov = out + MR + (size_t)MR * 160;
  const int gc = w * 64 + (l & 15);
#pragma unroll
  for (int sub = 0; sub < 2; ++sub) {
#pragma unroll
    for (int ih = 0; ih < 2; ++ih) {
      const int i = sub * 2 + ih;
#pragma unroll
      for (int j = 0; j < 4; ++j) {
        const int c = gc + j * 16;
        if (c > 400) continue;
        const float bj = bias[c];
#pragma unroll
        for (int r = 0; r < 4; ++r) {
          const int lr = ih * 16 + q4 + r;
          const int gr = m0 + sub * 32 + lr;
          const float v = acc[i][j][r] + bj;
          if (c < 160)      out[(size_t)MR + (size_t)gr * 160 + c] = v;
          else if (c < 400) mid[lr * 241 + (c - 160)] = v;
          else              out[gr] = v;
        }
      }
    }
    __syncthreads();
#pragma unroll
    for (int p = 0; p < 5; ++p) {
      const int q = p * 512 + tid;
      const int r32 = q / 80, j = q - r32 * 80;
      const int gr = m0 + sub * 32 + r32;
      const float av = mid[r32 * 241 + j];
      const float bv = mid[r32 * 241 + 80 + j];
      const float cv = mid[r32 * 241 + 160 + j];
      const float eb = __expf(bv), ebn = __expf(-bv);
      const float sh = 0.5f * (eb - ebn), ch = 0.5f * (eb + ebn);
      const float ea = __expf(av), ean = __expf(-av), ec = __expf(cv);
      f32x4 c4 = { ea * ch * ec, sh * ec, sh * ec, ean * ch * ec };
      *(f32x4*)(cov + (size_t)gr * 320 + 4 * j) = c4;
    }
    if (sub == 0) __syncthreads();
  }
}

// ---- weight transpose + bf16 convert ---------------------------------------
__global__ __launch_bounds__(256) void transpose_bf16(
    const float* __restrict__ W, __bf16* __restrict__ WT, int K, int N)
{
  __shared__ float t[32][33];
  const int b  = blockIdx.z;
  const int tx = threadIdx.x, ty = threadIdx.y;
  const int k0 = blockIdx.y * 32, n0 = blockIdx.x * 32;
  const float* Wb  = W  + (size_t)b * K * N;
  __bf16*      WTb = WT + (size_t)b * N * K;
#pragma unroll
  for (int r = 0; r < 4; ++r) {
    int kk = k0 + ty + r * 8;
    if (kk < K && n0 + tx < N) t[ty + r * 8][tx] = Wb[(size_t)kk * N + n0 + tx];
  }
  __syncthreads();
#pragma unroll
  for (int r = 0; r < 4; ++r) {
    int nn = n0 + ty + r * 8;
    if (nn < N && k0 + tx < K)
      WTb[(size_t)nn * K + k0 + tx] = (__bf16)t[tx][ty + r * 8];
  }
}

__global__ __launch_bounds__(256) void convert_bf16(
    const float* __restrict__ in, __bf16* __restrict__ out, int n)
{
  int i = blockIdx.x * 256 + threadIdx.x;
  if (i < n) out[i] = (__bf16)in[i];
}

// ---- iter-0 elementwise (init folded) --------------------------------------
__global__ __launch_bounds__(256) void ew_update0(
    const float* __restrict__ anchor, const float* __restrict__ fe,
    const float* __restrict__ snewsm, const __bf16* __restrict__ cnew,
    __bf16* __restrict__ s, __bf16* __restrict__ c)
{
  int q = blockIdx.x * 256 + threadIdx.x;
  if (q >= BA * 32) return;
  int ba = q >> 5;
  int dg = (q & 31) * 8;
  bf16_8 cn8 = *(const bf16_8*)(cnew + (size_t)ba * Dn + dg);
  float cn[8], m[8];
#pragma unroll
  for (int e = 0; e < 8; ++e) { cn[e] = (float)cn8[e]; m[e] = -3.402823466e38f; }
  size_t base = (size_t)ba * Tn * Dn + dg;
#pragma unroll
  for (int t = 0; t < Tn; ++t) {
    bf16_8 o8;
#pragma unroll
    for (int e = 0; e < 8; ++e) {
      float sn = snewsm[t * Dn + dg + e] * cn[e];
      m[e] = fmaxf(m[e], sn);
      o8[e] = (__bf16)(kAlpha * anchor[t * Dn + dg + e] + kBeta * sn);
    }
    *(bf16_8*)(s + base + t * Dn) = o8;
  }
  bf16_8 c8;
#pragma unroll
  for (int e = 0; e < 8; ++e)
    c8[e] = (__bf16)(kAlpha * fe[(size_t)ba * Dn + dg + e] + kBeta * m[e]);
  *(bf16_8*)(c + (size_t)ba * Dn + dg) = c8;
}

// ---------------------------------------------------------------------------
extern "C" void kernel_launch(void* const* d_in, const int* in_sizes, int n_in,
                              void* d_out, int out_size, void* d_ws, size_t ws_size,
                              hipStream_t stream) {
  const float* fe     = (const float*)d_in[0];
  const float* anchor = (const float*)d_in[1];
  const float* sW1 = (const float*)d_in[2];
  const float* sb1 = (const float*)d_in[3];
  const float* sW2 = (const float*)d_in[4];
  const float* sb2 = (const float*)d_in[5];
  const float* cW1 = (const float*)d_in[6];
  const float* cb1 = (const float*)d_in[7];
  const float* cW2 = (const float*)d_in[8];
  const float* cb2 = (const float*)d_in[9];
  const float* dW1 = (const float*)d_in[10];
  const float* db1 = (const float*)d_in[11];
  const float* dW2 = (const float*)d_in[12];
  const float* db2 = (const float*)d_in[13];
  float* out = (float*)d_out;

  // ---- workspace layout (bytes), total ~91.4 MB ----
  char* p = (char*)d_ws;
  __bf16* s_bf    = (__bf16*)(p + 0);            // 25,165,824
  __bf16* hd_bf   = (__bf16*)(p + 25165824);     // 50,331,648
  __bf16* c_bf    = (__bf16*)(p + 75497472);     //  4,194,304
  __bf16* cnew_bf = (__bf16*)(p + 79691776);     //  4,194,304
  __bf16* fe_bf   = (__bf16*)(p + 83886080);     //  4,194,304
  __bf16* sWT1    = (__bf16*)(p + 88080384);     //    655,360 each
  __bf16* sWT2    = (__bf16*)(p + 88735744);
  __bf16* cWT1    = (__bf16*)(p + 89391104);
  __bf16* cWT2    = (__bf16*)(p + 90046464);
  __bf16* dWT1    = (__bf16*)(p + 90701824);     //    262,144
  __bf16* dWT2    = (__bf16*)(p + 90963968);     //    410,624
  __bf16* anc_bf  = (__bf16*)(p + 91374592);     //      3,072
  __bf16* hsm_bf  = (__bf16*)(p + 91377664);     //      3,072
  float*  snewsm_f= (float* )(p + 91380736);     //      6,144

  auto gemm = [&](const __bf16* A, const __bf16* BT, const float* b, void* C,
                  int M, int N, int K, bool relu, bool outbf) {
    dim3 grid((N + 127) / 128, (M + 127) / 128);
    if (relu) {
      if (outbf) gemm_mfma<true,  true ><<<grid, 256, 0, stream>>>(A, BT, b, C, M, N, K);
      else       gemm_mfma<true,  false><<<grid, 256, 0, stream>>>(A, BT, b, C, M, N, K);
    } else {
      if (outbf) gemm_mfma<false, true ><<<grid, 256, 0, stream>>>(A, BT, b, C, M, N, K);
      else       gemm_mfma<false, false><<<grid, 256, 0, stream>>>(A, BT, b, C, M, N, K);
    }
  };

  // ---- weight prep ----
  {
    dim3 blk(32, 8);
    dim3 g88(8, 8, NBn);
    transpose_bf16<<<g88, blk, 0, stream>>>(sW1, sWT1, Dn, Dn);
    transpose_bf16<<<g88, blk, 0, stream>>>(sW2, sWT2, Dn, Dn);
    transpose_bf16<<<g88, blk, 0, stream>>>(cW1, cWT1, Dn, Dn);
    transpose_bf16<<<g88, blk, 0, stream>>>(cW2, cWT2, Dn, Dn);
    transpose_bf16<<<dim3(16, 8, 1), blk, 0, stream>>>(dW1, dWT1, Dn, Hn);
    transpose_bf16<<<dim3(13, 16, 1), blk, 0, stream>>>(dW2, dWT2, Hn, OUTn);
  }
  convert_bf16<<<(BA * Dn + 255) / 256, 256, 0, stream>>>(fe, fe_bf, BA * Dn);
  convert_bf16<<<(Tn * Dn + 255) / 256, 256, 0, stream>>>(anchor, anc_bf, Tn * Dn);

  const size_t WKK = (size_t)Dn * Dn;

  // ---- iteration 0 (s-branch on 6 anchor rows; c-branch fused MLP) ----
  gemm(anc_bf, sWT1, sb1, hsm_bf,   Tn, Dn, Dn, true,  true);
  gemm(hsm_bf, sWT2, sb2, snewsm_f, Tn, Dn, Dn, false, false);
  mlp2_c<<<BA / 32, 512, 0, stream>>>(fe_bf, cWT1, cb1, cWT2, cb2, cnew_bf);
  ew_update0<<<(BA * 32 + 255) / 256, 256, 0, stream>>>(anchor, fe, snewsm_f,
                                                        cnew_bf, s_bf, c_bf);

  // ---- iterations 1..4: ONE fused kernel each ----
  for (int i = 1; i < NBn; ++i) {
    mlp2_cs<<<MR / 96, 512, 0, stream>>>(
        s_bf,
        sWT1 + i * WKK, sb1 + i * Dn, sWT2 + i * WKK, sb2 + i * Dn,
        cWT1 + i * WKK, cb1 + i * Dn, cWT2 + i * WKK, cb2 + i * Dn,
        c_bf);
  }

  // ---- decoder ----
  gemm(s_bf, dWT1, db1, hd_bf, MR, Hn, Dn, true, true);
  decoder2_fused<<<MR / 64, 512, 0, stream>>>(hd_bf, dWT2, db2, out);
}